// Round 14
// baseline (109.914 us; speedup 1.0000x reference)
//
#include <hip/hip_runtime.h>
#include <math.h>

#define T_STEPS 3
#define N_NODES 100000
#define N_EDGES 1600000
#define N_E4    (N_EDGES / 4)
#define D 64

#define CS_BLOCKS 98        // ceil(100000/1024) colsum blocks per t (1024 rows each)

// Bucket parameters: 512-node buckets (R10-proven)
#define BKT_BITS 9
#define BKT_SIZE 512
#define NBKT 196            // ceil(100000/512)
#define NBKT_PAD 256
#define QSCALE 65536.0f     // 2^16
#define QINV   (1.0f / 65536.0f)

// Chunk parameters: 4096 edges per chunk, chunk == scatter block
#define SC_EPB 4096
#define SC_I4  1024
#define SC_CHUNKS 391       // ceil(1.6M / 4096)

// smatvec-in-K3: 512 threads, 4 lanes/row -> 128 rows/block
#define SMV_BLOCKS 782

// GRU-rows parameters
#define GR_PAD 68

// Fallback parameters
#define PACK_SCALE 1048576.0f
#define PACK_INV   (1.0f / 1048576.0f)

// ---------------------------------------------------------------------------
// FAST ws layout (float offsets) — atomic-free, no memsets (R10 layout):
//   [0,4800000)        recs[3][E] u32   overlaid (dead before K3):
//        [0,18816)         colsumP[3][98][64]
//        [150144,450432)   histChunk[3][391][256] u32
//   [4800000,5100288)  chunkPref[3][391][256] u32
//   [5100288,5101056)  bstart[3][256] u32
//   [5101056,5101248)  v[3][64]
//   [5101248,5401248)  s[3][N]
// rec format: (dst&511)<<17 | src   (src < 2^17)
// recs layout: bucket-contiguous per t (scatter writes runs, accum reads
// coalesced — the sort pays on the write side only).
// ---------------------------------------------------------------------------

// K1: fused prep — blocks [0,98): colsum partials of x_t (1024 rows/block);
// blocks [98,489): per-chunk dst bucket histograms.
__global__ __launch_bounds__(256) void prep_kernel(const float* __restrict__ x,
                                                   const int* __restrict__ dst,
                                                   float* __restrict__ colsumP,
                                                   unsigned* __restrict__ histChunk) {
    const int t = blockIdx.y;
    const int tid = threadIdx.x;
    __shared__ float red[16][64];
    __shared__ unsigned h[NBKT_PAD];

    if (blockIdx.x < CS_BLOCKS) {
        const int q = tid & 15;
        const int g = tid >> 4;
        const float4* xt = (const float4*)(x + (size_t)t * N_NODES * D);
        const int base = blockIdx.x * 1024;
        float sx = 0.f, sy = 0.f, sz = 0.f, sw = 0.f;
#pragma unroll 8
        for (int it = 0; it < 64; ++it) {
            const int r = base + g + 16 * it;
            if (r < N_NODES) {
                const float4 vv = xt[(size_t)r * 16 + q];
                sx += vv.x; sy += vv.y; sz += vv.z; sw += vv.w;
            }
        }
        red[g][q * 4 + 0] = sx;
        red[g][q * 4 + 1] = sy;
        red[g][q * 4 + 2] = sz;
        red[g][q * 4 + 3] = sw;
        __syncthreads();
        if (tid < 64) {
            float s = 0.f;
#pragma unroll
            for (int gg = 0; gg < 16; ++gg) s += red[gg][tid];
            colsumP[((size_t)t * CS_BLOCKS + blockIdx.x) * 64 + tid] = s;
        }
    } else {
        const int c = blockIdx.x - CS_BLOCKS;
        h[tid] = 0;
        __syncthreads();
        const int4* dp = (const int4*)(dst + (size_t)t * N_EDGES);
#pragma unroll
        for (int it = 0; it < 4; ++it) {
            const int i4 = c * SC_I4 + it * 256 + tid;
            if (i4 < N_E4) {
                const int4 d = dp[i4];
                atomicAdd(&h[d.x >> BKT_BITS], 1u);
                atomicAdd(&h[d.y >> BKT_BITS], 1u);
                atomicAdd(&h[d.z >> BKT_BITS], 1u);
                atomicAdd(&h[d.w >> BKT_BITS], 1u);
            }
        }
        __syncthreads();
        histChunk[((size_t)t * SC_CHUNKS + c) * NBKT_PAD + tid] = h[tid];
    }
}

__device__ __forceinline__ float fast_sigmoid(float v) {
    return 1.f / (1.f + __expf(-v));
}
__device__ __forceinline__ float fast_tanh(float v) {
    return 1.f - 2.f / (__expf(2.f * v) + 1.f);
}

// K2: blocks 0..15 GRU rows; block 16 bucket-total scan -> bstart;
// blocks 17..208 per-(chunk,bucket) exclusive prefixes -> chunkPref.
__global__ __launch_bounds__(256) void gru_rows_kernel(
    const float* __restrict__ colsumP, const float* __restrict__ iw,
    const float* __restrict__ Wz, const float* __restrict__ bz,
    const float* __restrict__ Wr, const float* __restrict__ br,
    const float* __restrict__ Wh, const float* __restrict__ bh,
    const float* __restrict__ Wp, const float* __restrict__ bp,
    const float* __restrict__ Wo, const unsigned* __restrict__ histChunk,
    unsigned* __restrict__ bstart, unsigned* __restrict__ chunkPref,
    float* __restrict__ v_out, float* __restrict__ w_final) {
    const int tid = threadIdx.x;

    if (blockIdx.x == 16) {
        __shared__ unsigned scn[NBKT_PAD];
        for (int t = 0; t < T_STEPS; ++t) {
            unsigned c = 0;
            for (int k = 0; k < SC_CHUNKS; ++k)
                c += histChunk[((size_t)t * SC_CHUNKS + k) * NBKT_PAD + tid];
            unsigned v = c;
            scn[tid] = v;
            __syncthreads();
            for (int off = 1; off < NBKT_PAD; off <<= 1) {
                const unsigned add = (tid >= off) ? scn[tid - off] : 0u;
                __syncthreads();
                v += add;
                scn[tid] = v;
                __syncthreads();
            }
            bstart[t * NBKT_PAD + tid] = (unsigned)(t * N_EDGES) + (v - c);
            __syncthreads();
        }
        return;
    }
    if (blockIdx.x >= 17) {
        const int idx = blockIdx.x - 17;      // 0..191
        const int t = idx >> 6;
        const int wid = tid >> 6, lane = tid & 63;
        const int b = (idx & 63) * 4 + wid;   // 0..255
        unsigned running = 0;
#pragma unroll
        for (int g = 0; g < 7; ++g) {
            const int c = g * 64 + lane;
            const unsigned val = (c < SC_CHUNKS)
                ? histChunk[((size_t)t * SC_CHUNKS + c) * NBKT_PAD + b] : 0u;
            unsigned incl = val;
#pragma unroll
            for (int off = 1; off < 64; off <<= 1) {
                const unsigned n = __shfl_up(incl, off);
                if (lane >= off) incl += n;
            }
            if (c < SC_CHUNKS)
                chunkPref[((size_t)t * SC_CHUNKS + c) * NBKT_PAD + b] = running + (incl - val);
            running += __shfl(incl, 63);
        }
        return;
    }

    // ---- GRU rows block ----
    __shared__ float BzT[64 * GR_PAD];
    __shared__ float BrT[64 * GR_PAD];
    __shared__ float BhT[64 * GR_PAD];
    __shared__ float w_lds[4 * 64];
    __shared__ float mean_s[192];
    __shared__ float ctx_s[192];
    __shared__ float czrh_s[576];

#pragma unroll
    for (int it = 0; it < 16; ++it) {
        const int idx = it * 256 + tid;
        const int k = idx >> 6, j = idx & 63;
        BzT[j * GR_PAD + k] = Wz[(64 + k) * 64 + j];
        BrT[j * GR_PAD + k] = Wr[(64 + k) * 64 + j];
        BhT[j * GR_PAD + k] = Wh[(64 + k) * 64 + j];
    }
    if (tid < 192) {
        const int t = tid >> 6, j = tid & 63;
        float s = 0.f;
        for (int bx = 0; bx < CS_BLOCKS; ++bx)
            s += colsumP[((size_t)t * CS_BLOCKS + bx) * 64 + j];
        mean_s[tid] = s * (1.f / (float)N_NODES);
    }
    __syncthreads();
    if (tid < 192) {
        const int t = tid >> 6, j = tid & 63;
        float c = bp[j];
        for (int k = 0; k < 64; ++k)
            c = fmaf(mean_s[t * 64 + k], Wp[k * 64 + j], c);
        ctx_s[tid] = c;
    }
    __syncthreads();
    for (int co = (tid >> 6); co < 9; co += 4) {
        const int t = co / 3, m = co - 3 * t, j = tid & 63;
        const float* W = (m == 0) ? Wz : (m == 1) ? Wr : Wh;
        const float* bb = (m == 0) ? bz : (m == 1) ? br : bh;
        float c = bb[j];
        for (int k = 0; k < 64; ++k)
            c = fmaf(ctx_s[t * 64 + k], W[k * 64 + j], c);
        czrh_s[co * 64 + j] = c;
    }
    __syncthreads();

    const int wid = tid >> 6, lane = tid & 63;
    const int row = blockIdx.x * 4 + wid;
    float* wrow = &w_lds[wid * 64];
    float w = iw[row * 64 + lane];
    const float wo = Wo[lane];

    for (int t = 0; t < T_STEPS; ++t) {
        wrow[lane] = w;
        __syncthreads();
        float az = 0.f, ar = 0.f;
#pragma unroll
        for (int k0 = 0; k0 < 64; k0 += 4) {
            const float4 wv = *(const float4*)&wrow[k0];
            const float4 z4 = *(const float4*)&BzT[lane * GR_PAD + k0];
            const float4 r4 = *(const float4*)&BrT[lane * GR_PAD + k0];
            az = fmaf(wv.x, z4.x, az); az = fmaf(wv.y, z4.y, az);
            az = fmaf(wv.z, z4.z, az); az = fmaf(wv.w, z4.w, az);
            ar = fmaf(wv.x, r4.x, ar); ar = fmaf(wv.y, r4.y, ar);
            ar = fmaf(wv.z, r4.z, ar); ar = fmaf(wv.w, r4.w, ar);
        }
        const float z = fast_sigmoid(az + czrh_s[(t * 3 + 0) * 64 + lane]);
        const float r = fast_sigmoid(ar + czrh_s[(t * 3 + 1) * 64 + lane]);
        const float rw = r * w;
        __syncthreads();
        wrow[lane] = rw;
        __syncthreads();
        float ah = 0.f;
#pragma unroll
        for (int k0 = 0; k0 < 64; k0 += 4) {
            const float4 wv = *(const float4*)&wrow[k0];
            const float4 h4 = *(const float4*)&BhT[lane * GR_PAD + k0];
            ah = fmaf(wv.x, h4.x, ah); ah = fmaf(wv.y, h4.y, ah);
            ah = fmaf(wv.z, h4.z, ah); ah = fmaf(wv.w, h4.w, ah);
        }
        const float h = fast_tanh(ah + czrh_s[(t * 3 + 2) * 64 + lane]);
        w = z * w + (1.f - z) * h;
        float vp = w * wo;
        vp += __shfl_xor(vp, 1);
        vp += __shfl_xor(vp, 2);
        vp += __shfl_xor(vp, 4);
        vp += __shfl_xor(vp, 8);
        vp += __shfl_xor(vp, 16);
        vp += __shfl_xor(vp, 32);
        if (lane == 0) v_out[t * 64 + row] = vp;
        __syncthreads();
    }
    w_final[row * 64 + lane] = w;
}

// K3: fused scatter (blocks [0,391)) + smatvec (blocks [391,1173)).
// Scatter: hist -> 2-barrier hybrid wave scan -> rank -> bucket-run writeout.
__global__ __launch_bounds__(512) void scat_smv_kernel(
    const float* __restrict__ x, const float* __restrict__ v,
    const int* __restrict__ src, const int* __restrict__ dst,
    const unsigned* __restrict__ bstart, const unsigned* __restrict__ chunkPref,
    unsigned* __restrict__ recs, float* __restrict__ s) {
    const int t = blockIdx.y;
    const int tid = threadIdx.x;
    __shared__ __align__(16) unsigned char lds_raw[23616];

    if (blockIdx.x >= SC_CHUNKS) {
        // ---- smatvec: 128 rows per block, 4 lanes per row ----
        float* vs = (float*)lds_raw;
        if (tid < 64) vs[tid] = v[t * 64 + tid];
        __syncthreads();
        const int row = (blockIdx.x - SC_CHUNKS) * 128 + (tid >> 2);
        const int l4 = tid & 3;
        if (row < N_NODES) {
            const float4* xr = (const float4*)(x + ((size_t)t * N_NODES + row) * D);
            float acc = 0.f;
#pragma unroll
            for (int i = 0; i < 4; ++i) {
                const int c = i * 4 + l4;
                const float4 xv = xr[c];
                acc += xv.x * vs[c * 4 + 0] + xv.y * vs[c * 4 + 1] +
                       xv.z * vs[c * 4 + 2] + xv.w * vs[c * 4 + 3];
            }
            acc += __shfl_xor(acc, 1);
            acc += __shfl_xor(acc, 2);
            if (l4 == 0) s[(size_t)t * N_NODES + row] = acc;
        }
        return;
    }

    // ---- scatter chunk c ----
    const int c = blockIdx.x;
    unsigned* recL = (unsigned*)lds_raw;                       // 4096 u32
    unsigned char* bktL = (unsigned char*)(lds_raw + 16384);   // 4096 u8
    unsigned* bh   = (unsigned*)(lds_raw + 20480);             // 256
    unsigned* lofs = bh + 256;                                 // 256
    unsigned* badj = lofs + 256;                               // 256
    unsigned* wsum = badj + 256;                               // 4

    if (tid < NBKT_PAD) bh[tid] = 0;
    __syncthreads();

    const int4* sp = (const int4*)(src + (size_t)t * N_EDGES);
    const int4* dp = (const int4*)(dst + (size_t)t * N_EDGES);

    unsigned rec[8];
    int bkt[8];
#pragma unroll
    for (int k = 0; k < 8; ++k) bkt[k] = -1;

#pragma unroll
    for (int it = 0; it < 2; ++it) {
        const int i4 = c * SC_I4 + it * 512 + tid;
        if (i4 < N_E4) {
            const int4 sv = sp[i4];
            const int4 dv = dp[i4];
            const int ss[4] = {sv.x, sv.y, sv.z, sv.w};
            const int dd[4] = {dv.x, dv.y, dv.z, dv.w};
#pragma unroll
            for (int j = 0; j < 4; ++j) {
                const int b = dd[j] >> BKT_BITS;
                rec[it * 4 + j] = ((unsigned)(dd[j] & (BKT_SIZE - 1)) << 17) |
                                  (unsigned)ss[j];
                bkt[it * 4 + j] = b;
                atomicAdd(&bh[b], 1u);
            }
        }
    }
    __syncthreads();
    // hybrid exclusive scan over 256 buckets: 4 waves x 64 + wave-sum combine
    unsigned cnt = 0, incl = 0;
    if (tid < NBKT_PAD) {
        cnt = bh[tid];
        incl = cnt;
#pragma unroll
        for (int off = 1; off < 64; off <<= 1) {
            const unsigned n = __shfl_up(incl, off);
            if ((tid & 63) >= off) incl += n;
        }
        if ((tid & 63) == 63) wsum[tid >> 6] = incl;
    }
    __syncthreads();
    if (tid < NBKT_PAD) {
        const int wv = tid >> 6;
        unsigned offs = 0;
#pragma unroll
        for (int k = 0; k < 3; ++k)
            if (k < wv) offs += wsum[k];
        const unsigned ex = offs + incl - cnt;
        lofs[tid] = ex;
        const unsigned base = bstart[t * NBKT_PAD + tid] +
                              chunkPref[((size_t)t * SC_CHUNKS + c) * NBKT_PAD + tid];
        badj[tid] = base - ex;   // mod 2^32 ok
    }
    __syncthreads();
#pragma unroll
    for (int k = 0; k < 8; ++k) {
        if (bkt[k] >= 0) {
            const unsigned pos = atomicAdd(&lofs[bkt[k]], 1u);
            recL[pos] = rec[k];
            bktL[pos] = (unsigned char)bkt[k];
        }
    }
    __syncthreads();
    const int nrec = min(SC_EPB, N_EDGES - c * SC_EPB);
    for (int i = tid; i < nrec; i += 512) {
        const unsigned b = bktL[i];
        recs[badj[b] + (unsigned)i] = recL[i];
    }
}

// K4: per-bucket accumulate — coalesced contiguous record reads,
// gather s[src] (L2), integer u64 LDS bins (deterministic), finalize.
__global__ __launch_bounds__(256) void accum_kernel(const unsigned* __restrict__ recs,
                                                    const unsigned* __restrict__ start,
                                                    const float* __restrict__ s,
                                                    const float* __restrict__ bo,
                                                    float* __restrict__ out) {
    const int b = blockIdx.x;
    const int t = blockIdx.y;
    const int tid = threadIdx.x;
    __shared__ unsigned long long bins[BKT_SIZE];
    bins[tid] = 0ULL;
    bins[tid + 256] = 0ULL;
    __syncthreads();
    const float* st = s + (size_t)t * N_NODES;
    const unsigned s0 = start[t * NBKT_PAD + b];
    const unsigned s1 = start[t * NBKT_PAD + b + 1];
    for (unsigned i = s0 + tid; i < s1; i += 256) {
        const unsigned rec = recs[i];
        const unsigned dl = rec >> 17;
        const long long q = llrintf(st[rec & 0x1FFFFu] * QSCALE);
        atomicAdd(&bins[dl],
                  (unsigned long long)((1ULL << 41) + (unsigned long long)q));
    }
    __syncthreads();
    const float bo0 = bo[0];
#pragma unroll
    for (int k = 0; k < 2; ++k) {
        const int i = tid + k * 256;
        const int node = b * BKT_SIZE + i;
        if (node < N_NODES) {
            const unsigned long long tot = bins[i];
            const unsigned long long deg = (tot + (1ULL << 40)) >> 41;
            const long long rem = (long long)(tot - (deg << 41));
            const float acc = (float)rem * QINV;
            out[(size_t)t * N_NODES + node] = bo0 + acc / fmaxf((float)deg, 1.f);
        }
    }
}

// ---------- fallback path: packed global atomics ----------

__global__ __launch_bounds__(256) void smatvec_kernel(const float* __restrict__ x,
                                                      const float* __restrict__ v,
                                                      float* __restrict__ s) {
    const int t = blockIdx.y;
    const int tid = threadIdx.x;
    const int l4 = tid & 3;
    const int rloc = tid >> 2;
    __shared__ float vs[64];
    if (tid < 64) vs[tid] = v[t * 64 + tid];
    __syncthreads();
    const int row = blockIdx.x * 64 + rloc;
    if (row < N_NODES) {
        const float4* xr = (const float4*)(x + ((size_t)t * N_NODES + row) * D);
        float acc = 0.f;
#pragma unroll
        for (int i = 0; i < 4; ++i) {
            const int c = i * 4 + l4;
            const float4 xv = xr[c];
            acc += xv.x * vs[c * 4 + 0] + xv.y * vs[c * 4 + 1] +
                   xv.z * vs[c * 4 + 2] + xv.w * vs[c * 4 + 3];
        }
        acc += __shfl_xor(acc, 1);
        acc += __shfl_xor(acc, 2);
        if (l4 == 0) s[(size_t)t * N_NODES + row] = acc;
    }
}

__global__ __launch_bounds__(256) void edge_kernel(const int* __restrict__ src,
                                                   const int* __restrict__ dst,
                                                   const float* __restrict__ s,
                                                   unsigned long long* __restrict__ packed) {
    const int t = blockIdx.y;
    const int e4 = blockIdx.x * 256 + threadIdx.x;
    if (e4 * 4 >= N_EDGES) return;
    const int4* sp = (const int4*)(src + (size_t)t * N_EDGES);
    const int4* dp = (const int4*)(dst + (size_t)t * N_EDGES);
    const float* st = s + (size_t)t * N_NODES;
    unsigned long long* pk = packed + (size_t)t * N_NODES;
    const int4 s4 = sp[e4];
    const int4 d4 = dp[e4];
    const float v0 = st[s4.x], v1 = st[s4.y], v2 = st[s4.z], v3 = st[s4.w];
    const unsigned long long base = 1ULL << 41;
    atomicAdd(&pk[d4.x], base + (unsigned long long)(long long)llrintf(v0 * PACK_SCALE));
    atomicAdd(&pk[d4.y], base + (unsigned long long)(long long)llrintf(v1 * PACK_SCALE));
    atomicAdd(&pk[d4.z], base + (unsigned long long)(long long)llrintf(v2 * PACK_SCALE));
    atomicAdd(&pk[d4.w], base + (unsigned long long)(long long)llrintf(v3 * PACK_SCALE));
}

__global__ __launch_bounds__(256) void out_kernel(const unsigned long long* __restrict__ packed,
                                                  const float* __restrict__ bo,
                                                  float* __restrict__ out) {
    const int i = blockIdx.x * 256 + threadIdx.x;
    if (i < T_STEPS * N_NODES) {
        const unsigned long long tot = packed[i];
        const unsigned long long deg = (tot + (1ULL << 40)) >> 41;
        const long long rem = (long long)(tot - (deg << 41));
        const float acc = (float)rem * PACK_INV;
        out[i] = bo[0] + acc / fmaxf((float)deg, 1.0f);
    }
}

extern "C" void kernel_launch(void* const* d_in, const int* in_sizes, int n_in,
                              void* d_out, int out_size, void* d_ws, size_t ws_size,
                              hipStream_t stream) {
    const float* x  = (const float*)d_in[0];
    const int* src  = (const int*)d_in[1];
    const int* dst  = (const int*)d_in[2];
    const float* iw = (const float*)d_in[3];
    const float* Wz = (const float*)d_in[4];
    const float* bz = (const float*)d_in[5];
    const float* Wr = (const float*)d_in[6];
    const float* br = (const float*)d_in[7];
    const float* Wh = (const float*)d_in[8];
    const float* bh = (const float*)d_in[9];
    const float* Wp = (const float*)d_in[10];
    const float* bp = (const float*)d_in[11];
    const float* Wo = (const float*)d_in[12];
    const float* bo = (const float*)d_in[13];
    float* out = (float*)d_out;   // [3*N outs][64*64 w_final]
    float* ws  = (float*)d_ws;

    const size_t FAST_NEED = (size_t)5401248 * sizeof(float);
    if (ws_size >= FAST_NEED) {
        unsigned* recs      = (unsigned*)ws;              // [0,4800000)
        float* colsumP      = ws;                         // [0,18816) dead before K3
        unsigned* histChunk = (unsigned*)(ws + 150144);   // [150144,450432) dead before K3
        unsigned* chunkPref = (unsigned*)(ws + 4800000);  // 300288 u32
        unsigned* bstart    = (unsigned*)(ws + 5100288);  // 768 u32
        float* vbuf         = ws + 5101056;               // 192
        float* sbuf         = ws + 5101248;               // 300000

        prep_kernel<<<dim3(CS_BLOCKS + SC_CHUNKS, 3), 256, 0, stream>>>(x, dst,
                                                                        colsumP, histChunk);
        gru_rows_kernel<<<209, 256, 0, stream>>>(colsumP, iw, Wz, bz, Wr, br, Wh, bh,
                                                 Wp, bp, Wo, histChunk, bstart, chunkPref,
                                                 vbuf, out + (size_t)T_STEPS * N_NODES);
        scat_smv_kernel<<<dim3(SC_CHUNKS + SMV_BLOCKS, 3), 512, 0, stream>>>(
            x, vbuf, src, dst, bstart, chunkPref, recs, sbuf);
        accum_kernel<<<dim3(NBKT, 3), 256, 0, stream>>>(recs, bstart, sbuf, bo, out);
    } else {
        float* colsumP = ws;                                        // 18816
        float* vbuf    = ws + 150144;                               // 192
        float* sbuf    = ws + 150336;                               // 300000
        unsigned long long* packed = (unsigned long long*)(ws + 450336); // 300000 u64

        hipMemsetAsync(packed, 0, (size_t)600000 * sizeof(float), stream);

        prep_kernel<<<dim3(CS_BLOCKS, 3), 256, 0, stream>>>(x, dst, colsumP,
                                                            (unsigned*)nullptr);
        gru_rows_kernel<<<16, 256, 0, stream>>>(colsumP, iw, Wz, bz, Wr, br, Wh, bh,
                                                Wp, bp, Wo, (unsigned*)nullptr,
                                                (unsigned*)nullptr, (unsigned*)nullptr,
                                                vbuf, out + (size_t)T_STEPS * N_NODES);
        smatvec_kernel<<<dim3(1563, 3), 256, 0, stream>>>(x, vbuf, sbuf);
        edge_kernel<<<dim3(1563, 3), 256, 0, stream>>>(src, dst, sbuf, packed);
        out_kernel<<<1172, 256, 0, stream>>>(packed, bo, out);
    }
}

// Round 15
// 100.540 us; speedup vs baseline: 1.0932x; 1.0932x over previous
//
#include <hip/hip_runtime.h>
#include <math.h>

#define T_STEPS 3
#define N_NODES 100000
#define N_EDGES 1600000
#define N_E4    (N_EDGES / 4)
#define D 64

#define CS_BLOCKS 391       // ceil(100000/256) colsum blocks per t (256 rows each)

// Bucket parameters: 512-node buckets (R10-proven)
#define BKT_BITS 9
#define BKT_SIZE 512
#define NBKT 196            // ceil(100000/512)
#define NBKT_PAD 256
#define QSCALE 65536.0f     // 2^16
#define QINV   (1.0f / 65536.0f)

// Chunk parameters: 4096 edges per chunk, chunk == scatter block
#define SC_EPB 4096
#define SC_I4  1024
#define SC_CHUNKS 391       // ceil(1.6M / 4096)

// smatvec-in-K3: 512 threads, 4 lanes/row -> 128 rows/block
#define SMV_BLOCKS 782

// GRU-rows parameters
#define GR_PAD 68

// Fallback parameters
#define PACK_SCALE 1048576.0f
#define PACK_INV   (1.0f / 1048576.0f)

// ---------------------------------------------------------------------------
// FAST ws layout (float offsets) — atomic-free, no memsets (R13 layout):
//   [0,4800000)        recs[3][E] u32   overlaid (dead before K3):
//        [0,75072)         colsumP[3][391][64]
//        [150144,450432)   histChunk[3][391][256] u32
//   [4800000,5100288)  chunkPref[3][391][256] u32
//   [5100288,5101056)  bstart[3][256] u32
//   [5101056,5101248)  v[3][64]
//   [5101248,5401248)  s[3][N]
// rec format: (dst&511)<<17 | src   (src < 2^17)
// recs layout: bucket-contiguous per t (scatter writes runs, accum reads
// coalesced — the sort pays on the write side only).
// ---------------------------------------------------------------------------

// K1: fused prep — blocks [0,391): colsum partials of x_t (256 rows/block);
// blocks [391,782): per-chunk dst bucket histograms.
__global__ __launch_bounds__(256) void prep_kernel(const float* __restrict__ x,
                                                   const int* __restrict__ dst,
                                                   float* __restrict__ colsumP,
                                                   unsigned* __restrict__ histChunk) {
    const int t = blockIdx.y;
    const int tid = threadIdx.x;
    __shared__ float red[16][64];
    __shared__ unsigned h[NBKT_PAD];

    if (blockIdx.x < CS_BLOCKS) {
        const int q = tid & 15;
        const int g = tid >> 4;
        const float4* xt = (const float4*)(x + (size_t)t * N_NODES * D);
        const int base = blockIdx.x * 256;
        float sx = 0.f, sy = 0.f, sz = 0.f, sw = 0.f;
#pragma unroll 4
        for (int it = 0; it < 16; ++it) {
            const int r = base + g + 16 * it;
            if (r < N_NODES) {
                const float4 vv = xt[(size_t)r * 16 + q];
                sx += vv.x; sy += vv.y; sz += vv.z; sw += vv.w;
            }
        }
        red[g][q * 4 + 0] = sx;
        red[g][q * 4 + 1] = sy;
        red[g][q * 4 + 2] = sz;
        red[g][q * 4 + 3] = sw;
        __syncthreads();
        if (tid < 64) {
            float s = 0.f;
#pragma unroll
            for (int gg = 0; gg < 16; ++gg) s += red[gg][tid];
            colsumP[((size_t)t * CS_BLOCKS + blockIdx.x) * 64 + tid] = s;
        }
    } else {
        const int c = blockIdx.x - CS_BLOCKS;
        h[tid] = 0;
        __syncthreads();
        const int4* dp = (const int4*)(dst + (size_t)t * N_EDGES);
#pragma unroll
        for (int it = 0; it < 4; ++it) {
            const int i4 = c * SC_I4 + it * 256 + tid;
            if (i4 < N_E4) {
                const int4 d = dp[i4];
                atomicAdd(&h[d.x >> BKT_BITS], 1u);
                atomicAdd(&h[d.y >> BKT_BITS], 1u);
                atomicAdd(&h[d.z >> BKT_BITS], 1u);
                atomicAdd(&h[d.w >> BKT_BITS], 1u);
            }
        }
        __syncthreads();
        histChunk[((size_t)t * SC_CHUNKS + c) * NBKT_PAD + tid] = h[tid];
    }
}

__device__ __forceinline__ float fast_sigmoid(float v) {
    return 1.f / (1.f + __expf(-v));
}
__device__ __forceinline__ float fast_tanh(float v) {
    return 1.f - 2.f / (__expf(2.f * v) + 1.f);
}

// K2: blocks 0..15 GRU rows; block 16 bucket-total scan -> bstart;
// blocks 17..208 per-(chunk,bucket) exclusive prefixes -> chunkPref.
__global__ __launch_bounds__(256) void gru_rows_kernel(
    const float* __restrict__ colsumP, const float* __restrict__ iw,
    const float* __restrict__ Wz, const float* __restrict__ bz,
    const float* __restrict__ Wr, const float* __restrict__ br,
    const float* __restrict__ Wh, const float* __restrict__ bh,
    const float* __restrict__ Wp, const float* __restrict__ bp,
    const float* __restrict__ Wo, const unsigned* __restrict__ histChunk,
    unsigned* __restrict__ bstart, unsigned* __restrict__ chunkPref,
    float* __restrict__ v_out, float* __restrict__ w_final) {
    const int tid = threadIdx.x;

    if (blockIdx.x == 16) {
        __shared__ unsigned scn[NBKT_PAD];
        for (int t = 0; t < T_STEPS; ++t) {
            unsigned c = 0;
            for (int k = 0; k < SC_CHUNKS; ++k)
                c += histChunk[((size_t)t * SC_CHUNKS + k) * NBKT_PAD + tid];
            unsigned v = c;
            scn[tid] = v;
            __syncthreads();
            for (int off = 1; off < NBKT_PAD; off <<= 1) {
                const unsigned add = (tid >= off) ? scn[tid - off] : 0u;
                __syncthreads();
                v += add;
                scn[tid] = v;
                __syncthreads();
            }
            bstart[t * NBKT_PAD + tid] = (unsigned)(t * N_EDGES) + (v - c);
            __syncthreads();
        }
        return;
    }
    if (blockIdx.x >= 17) {
        const int idx = blockIdx.x - 17;      // 0..191
        const int t = idx >> 6;
        const int wid = tid >> 6, lane = tid & 63;
        const int b = (idx & 63) * 4 + wid;   // 0..255
        unsigned running = 0;
#pragma unroll
        for (int g = 0; g < 7; ++g) {
            const int c = g * 64 + lane;
            const unsigned val = (c < SC_CHUNKS)
                ? histChunk[((size_t)t * SC_CHUNKS + c) * NBKT_PAD + b] : 0u;
            unsigned incl = val;
#pragma unroll
            for (int off = 1; off < 64; off <<= 1) {
                const unsigned n = __shfl_up(incl, off);
                if (lane >= off) incl += n;
            }
            if (c < SC_CHUNKS)
                chunkPref[((size_t)t * SC_CHUNKS + c) * NBKT_PAD + b] = running + (incl - val);
            running += __shfl(incl, 63);
        }
        return;
    }

    // ---- GRU rows block ----
    __shared__ float BzT[64 * GR_PAD];
    __shared__ float BrT[64 * GR_PAD];
    __shared__ float BhT[64 * GR_PAD];
    __shared__ float w_lds[4 * 64];
    __shared__ float mean_s[192];
    __shared__ float ctx_s[192];
    __shared__ float czrh_s[576];

#pragma unroll
    for (int it = 0; it < 16; ++it) {
        const int idx = it * 256 + tid;
        const int k = idx >> 6, j = idx & 63;
        BzT[j * GR_PAD + k] = Wz[(64 + k) * 64 + j];
        BrT[j * GR_PAD + k] = Wr[(64 + k) * 64 + j];
        BhT[j * GR_PAD + k] = Wh[(64 + k) * 64 + j];
    }
    if (tid < 192) {
        const int t = tid >> 6, j = tid & 63;
        float s = 0.f;
        for (int bx = 0; bx < CS_BLOCKS; ++bx)
            s += colsumP[((size_t)t * CS_BLOCKS + bx) * 64 + j];
        mean_s[tid] = s * (1.f / (float)N_NODES);
    }
    __syncthreads();
    if (tid < 192) {
        const int t = tid >> 6, j = tid & 63;
        float c = bp[j];
        for (int k = 0; k < 64; ++k)
            c = fmaf(mean_s[t * 64 + k], Wp[k * 64 + j], c);
        ctx_s[tid] = c;
    }
    __syncthreads();
    for (int co = (tid >> 6); co < 9; co += 4) {
        const int t = co / 3, m = co - 3 * t, j = tid & 63;
        const float* W = (m == 0) ? Wz : (m == 1) ? Wr : Wh;
        const float* bb = (m == 0) ? bz : (m == 1) ? br : bh;
        float c = bb[j];
        for (int k = 0; k < 64; ++k)
            c = fmaf(ctx_s[t * 64 + k], W[k * 64 + j], c);
        czrh_s[co * 64 + j] = c;
    }
    __syncthreads();

    const int wid = tid >> 6, lane = tid & 63;
    const int row = blockIdx.x * 4 + wid;
    float* wrow = &w_lds[wid * 64];
    float w = iw[row * 64 + lane];
    const float wo = Wo[lane];

    for (int t = 0; t < T_STEPS; ++t) {
        wrow[lane] = w;
        __syncthreads();
        float az = 0.f, ar = 0.f;
#pragma unroll
        for (int k0 = 0; k0 < 64; k0 += 4) {
            const float4 wv = *(const float4*)&wrow[k0];
            const float4 z4 = *(const float4*)&BzT[lane * GR_PAD + k0];
            const float4 r4 = *(const float4*)&BrT[lane * GR_PAD + k0];
            az = fmaf(wv.x, z4.x, az); az = fmaf(wv.y, z4.y, az);
            az = fmaf(wv.z, z4.z, az); az = fmaf(wv.w, z4.w, az);
            ar = fmaf(wv.x, r4.x, ar); ar = fmaf(wv.y, r4.y, ar);
            ar = fmaf(wv.z, r4.z, ar); ar = fmaf(wv.w, r4.w, ar);
        }
        const float z = fast_sigmoid(az + czrh_s[(t * 3 + 0) * 64 + lane]);
        const float r = fast_sigmoid(ar + czrh_s[(t * 3 + 1) * 64 + lane]);
        const float rw = r * w;
        __syncthreads();
        wrow[lane] = rw;
        __syncthreads();
        float ah = 0.f;
#pragma unroll
        for (int k0 = 0; k0 < 64; k0 += 4) {
            const float4 wv = *(const float4*)&wrow[k0];
            const float4 h4 = *(const float4*)&BhT[lane * GR_PAD + k0];
            ah = fmaf(wv.x, h4.x, ah); ah = fmaf(wv.y, h4.y, ah);
            ah = fmaf(wv.z, h4.z, ah); ah = fmaf(wv.w, h4.w, ah);
        }
        const float h = fast_tanh(ah + czrh_s[(t * 3 + 2) * 64 + lane]);
        w = z * w + (1.f - z) * h;
        float vp = w * wo;
        vp += __shfl_xor(vp, 1);
        vp += __shfl_xor(vp, 2);
        vp += __shfl_xor(vp, 4);
        vp += __shfl_xor(vp, 8);
        vp += __shfl_xor(vp, 16);
        vp += __shfl_xor(vp, 32);
        if (lane == 0) v_out[t * 64 + row] = vp;
        __syncthreads();
    }
    w_final[row * 64 + lane] = w;
}

// K3: fused scatter (blocks [0,391)) + smatvec (blocks [391,1173)).
// Scatter: hist -> 2-barrier hybrid wave scan -> rank -> bucket-run writeout.
__global__ __launch_bounds__(512) void scat_smv_kernel(
    const float* __restrict__ x, const float* __restrict__ v,
    const int* __restrict__ src, const int* __restrict__ dst,
    const unsigned* __restrict__ bstart, const unsigned* __restrict__ chunkPref,
    unsigned* __restrict__ recs, float* __restrict__ s) {
    const int t = blockIdx.y;
    const int tid = threadIdx.x;
    __shared__ __align__(16) unsigned char lds_raw[23616];

    if (blockIdx.x >= SC_CHUNKS) {
        // ---- smatvec: 128 rows per block, 4 lanes per row ----
        float* vs = (float*)lds_raw;
        if (tid < 64) vs[tid] = v[t * 64 + tid];
        __syncthreads();
        const int row = (blockIdx.x - SC_CHUNKS) * 128 + (tid >> 2);
        const int l4 = tid & 3;
        if (row < N_NODES) {
            const float4* xr = (const float4*)(x + ((size_t)t * N_NODES + row) * D);
            float acc = 0.f;
#pragma unroll
            for (int i = 0; i < 4; ++i) {
                const int c = i * 4 + l4;
                const float4 xv = xr[c];
                acc += xv.x * vs[c * 4 + 0] + xv.y * vs[c * 4 + 1] +
                       xv.z * vs[c * 4 + 2] + xv.w * vs[c * 4 + 3];
            }
            acc += __shfl_xor(acc, 1);
            acc += __shfl_xor(acc, 2);
            if (l4 == 0) s[(size_t)t * N_NODES + row] = acc;
        }
        return;
    }

    // ---- scatter chunk c ----
    const int c = blockIdx.x;
    unsigned* recL = (unsigned*)lds_raw;                       // 4096 u32
    unsigned char* bktL = (unsigned char*)(lds_raw + 16384);   // 4096 u8
    unsigned* bh   = (unsigned*)(lds_raw + 20480);             // 256
    unsigned* lofs = bh + 256;                                 // 256
    unsigned* badj = lofs + 256;                               // 256
    unsigned* wsum = badj + 256;                               // 4

    if (tid < NBKT_PAD) bh[tid] = 0;
    __syncthreads();

    const int4* sp = (const int4*)(src + (size_t)t * N_EDGES);
    const int4* dp = (const int4*)(dst + (size_t)t * N_EDGES);

    unsigned rec[8];
    int bkt[8];
#pragma unroll
    for (int k = 0; k < 8; ++k) bkt[k] = -1;

#pragma unroll
    for (int it = 0; it < 2; ++it) {
        const int i4 = c * SC_I4 + it * 512 + tid;
        if (i4 < N_E4) {
            const int4 sv = sp[i4];
            const int4 dv = dp[i4];
            const int ss[4] = {sv.x, sv.y, sv.z, sv.w};
            const int dd[4] = {dv.x, dv.y, dv.z, dv.w};
#pragma unroll
            for (int j = 0; j < 4; ++j) {
                const int b = dd[j] >> BKT_BITS;
                rec[it * 4 + j] = ((unsigned)(dd[j] & (BKT_SIZE - 1)) << 17) |
                                  (unsigned)ss[j];
                bkt[it * 4 + j] = b;
                atomicAdd(&bh[b], 1u);
            }
        }
    }
    __syncthreads();
    // hybrid exclusive scan over 256 buckets: 4 waves x 64 + wave-sum combine
    unsigned cnt = 0, incl = 0;
    if (tid < NBKT_PAD) {
        cnt = bh[tid];
        incl = cnt;
#pragma unroll
        for (int off = 1; off < 64; off <<= 1) {
            const unsigned n = __shfl_up(incl, off);
            if ((tid & 63) >= off) incl += n;
        }
        if ((tid & 63) == 63) wsum[tid >> 6] = incl;
    }
    __syncthreads();
    if (tid < NBKT_PAD) {
        const int wv = tid >> 6;
        unsigned offs = 0;
#pragma unroll
        for (int k = 0; k < 3; ++k)
            if (k < wv) offs += wsum[k];
        const unsigned ex = offs + incl - cnt;
        lofs[tid] = ex;
        const unsigned base = bstart[t * NBKT_PAD + tid] +
                              chunkPref[((size_t)t * SC_CHUNKS + c) * NBKT_PAD + tid];
        badj[tid] = base - ex;   // mod 2^32 ok
    }
    __syncthreads();
#pragma unroll
    for (int k = 0; k < 8; ++k) {
        if (bkt[k] >= 0) {
            const unsigned pos = atomicAdd(&lofs[bkt[k]], 1u);
            recL[pos] = rec[k];
            bktL[pos] = (unsigned char)bkt[k];
        }
    }
    __syncthreads();
    const int nrec = min(SC_EPB, N_EDGES - c * SC_EPB);
    for (int i = tid; i < nrec; i += 512) {
        const unsigned b = bktL[i];
        recs[badj[b] + (unsigned)i] = recL[i];
    }
}

// K4: per-bucket accumulate — coalesced contiguous record reads,
// gather s[src] (L2), integer u64 LDS bins (deterministic), finalize.
__global__ __launch_bounds__(256) void accum_kernel(const unsigned* __restrict__ recs,
                                                    const unsigned* __restrict__ start,
                                                    const float* __restrict__ s,
                                                    const float* __restrict__ bo,
                                                    float* __restrict__ out) {
    const int b = blockIdx.x;
    const int t = blockIdx.y;
    const int tid = threadIdx.x;
    __shared__ unsigned long long bins[BKT_SIZE];
    bins[tid] = 0ULL;
    bins[tid + 256] = 0ULL;
    __syncthreads();
    const float* st = s + (size_t)t * N_NODES;
    const unsigned s0 = start[t * NBKT_PAD + b];
    const unsigned s1 = start[t * NBKT_PAD + b + 1];
    for (unsigned i = s0 + tid; i < s1; i += 256) {
        const unsigned rec = recs[i];
        const unsigned dl = rec >> 17;
        const long long q = llrintf(st[rec & 0x1FFFFu] * QSCALE);
        atomicAdd(&bins[dl],
                  (unsigned long long)((1ULL << 41) + (unsigned long long)q));
    }
    __syncthreads();
    const float bo0 = bo[0];
#pragma unroll
    for (int k = 0; k < 2; ++k) {
        const int i = tid + k * 256;
        const int node = b * BKT_SIZE + i;
        if (node < N_NODES) {
            const unsigned long long tot = bins[i];
            const unsigned long long deg = (tot + (1ULL << 40)) >> 41;
            const long long rem = (long long)(tot - (deg << 41));
            const float acc = (float)rem * QINV;
            out[(size_t)t * N_NODES + node] = bo0 + acc / fmaxf((float)deg, 1.f);
        }
    }
}

// ---------- fallback path: packed global atomics ----------

__global__ __launch_bounds__(256) void smatvec_kernel(const float* __restrict__ x,
                                                      const float* __restrict__ v,
                                                      float* __restrict__ s) {
    const int t = blockIdx.y;
    const int tid = threadIdx.x;
    const int l4 = tid & 3;
    const int rloc = tid >> 2;
    __shared__ float vs[64];
    if (tid < 64) vs[tid] = v[t * 64 + tid];
    __syncthreads();
    const int row = blockIdx.x * 64 + rloc;
    if (row < N_NODES) {
        const float4* xr = (const float4*)(x + ((size_t)t * N_NODES + row) * D);
        float acc = 0.f;
#pragma unroll
        for (int i = 0; i < 4; ++i) {
            const int c = i * 4 + l4;
            const float4 xv = xr[c];
            acc += xv.x * vs[c * 4 + 0] + xv.y * vs[c * 4 + 1] +
                   xv.z * vs[c * 4 + 2] + xv.w * vs[c * 4 + 3];
        }
        acc += __shfl_xor(acc, 1);
        acc += __shfl_xor(acc, 2);
        if (l4 == 0) s[(size_t)t * N_NODES + row] = acc;
    }
}

__global__ __launch_bounds__(256) void edge_kernel(const int* __restrict__ src,
                                                   const int* __restrict__ dst,
                                                   const float* __restrict__ s,
                                                   unsigned long long* __restrict__ packed) {
    const int t = blockIdx.y;
    const int e4 = blockIdx.x * 256 + threadIdx.x;
    if (e4 * 4 >= N_EDGES) return;
    const int4* sp = (const int4*)(src + (size_t)t * N_EDGES);
    const int4* dp = (const int4*)(dst + (size_t)t * N_EDGES);
    const float* st = s + (size_t)t * N_NODES;
    unsigned long long* pk = packed + (size_t)t * N_NODES;
    const int4 s4 = sp[e4];
    const int4 d4 = dp[e4];
    const float v0 = st[s4.x], v1 = st[s4.y], v2 = st[s4.z], v3 = st[s4.w];
    const unsigned long long base = 1ULL << 41;
    atomicAdd(&pk[d4.x], base + (unsigned long long)(long long)llrintf(v0 * PACK_SCALE));
    atomicAdd(&pk[d4.y], base + (unsigned long long)(long long)llrintf(v1 * PACK_SCALE));
    atomicAdd(&pk[d4.z], base + (unsigned long long)(long long)llrintf(v2 * PACK_SCALE));
    atomicAdd(&pk[d4.w], base + (unsigned long long)(long long)llrintf(v3 * PACK_SCALE));
}

__global__ __launch_bounds__(256) void out_kernel(const unsigned long long* __restrict__ packed,
                                                  const float* __restrict__ bo,
                                                  float* __restrict__ out) {
    const int i = blockIdx.x * 256 + threadIdx.x;
    if (i < T_STEPS * N_NODES) {
        const unsigned long long tot = packed[i];
        const unsigned long long deg = (tot + (1ULL << 40)) >> 41;
        const long long rem = (long long)(tot - (deg << 41));
        const float acc = (float)rem * PACK_INV;
        out[i] = bo[0] + acc / fmaxf((float)deg, 1.0f);
    }
}

extern "C" void kernel_launch(void* const* d_in, const int* in_sizes, int n_in,
                              void* d_out, int out_size, void* d_ws, size_t ws_size,
                              hipStream_t stream) {
    const float* x  = (const float*)d_in[0];
    const int* src  = (const int*)d_in[1];
    const int* dst  = (const int*)d_in[2];
    const float* iw = (const float*)d_in[3];
    const float* Wz = (const float*)d_in[4];
    const float* bz = (const float*)d_in[5];
    const float* Wr = (const float*)d_in[6];
    const float* br = (const float*)d_in[7];
    const float* Wh = (const float*)d_in[8];
    const float* bh = (const float*)d_in[9];
    const float* Wp = (const float*)d_in[10];
    const float* bp = (const float*)d_in[11];
    const float* Wo = (const float*)d_in[12];
    const float* bo = (const float*)d_in[13];
    float* out = (float*)d_out;   // [3*N outs][64*64 w_final]
    float* ws  = (float*)d_ws;

    const size_t FAST_NEED = (size_t)5401248 * sizeof(float);
    if (ws_size >= FAST_NEED) {
        unsigned* recs      = (unsigned*)ws;              // [0,4800000)
        float* colsumP      = ws;                         // [0,75072) dead before K3
        unsigned* histChunk = (unsigned*)(ws + 150144);   // [150144,450432) dead before K3
        unsigned* chunkPref = (unsigned*)(ws + 4800000);  // 300288 u32
        unsigned* bstart    = (unsigned*)(ws + 5100288);  // 768 u32
        float* vbuf         = ws + 5101056;               // 192
        float* sbuf         = ws + 5101248;               // 300000

        prep_kernel<<<dim3(CS_BLOCKS + SC_CHUNKS, 3), 256, 0, stream>>>(x, dst,
                                                                        colsumP, histChunk);
        gru_rows_kernel<<<209, 256, 0, stream>>>(colsumP, iw, Wz, bz, Wr, br, Wh, bh,
                                                 Wp, bp, Wo, histChunk, bstart, chunkPref,
                                                 vbuf, out + (size_t)T_STEPS * N_NODES);
        scat_smv_kernel<<<dim3(SC_CHUNKS + SMV_BLOCKS, 3), 512, 0, stream>>>(
            x, vbuf, src, dst, bstart, chunkPref, recs, sbuf);
        accum_kernel<<<dim3(NBKT, 3), 256, 0, stream>>>(recs, bstart, sbuf, bo, out);
    } else {
        float* colsumP = ws;                                        // 75072
        float* vbuf    = ws + 150144;                               // 192
        float* sbuf    = ws + 150336;                               // 300000
        unsigned long long* packed = (unsigned long long*)(ws + 450336); // 300000 u64

        hipMemsetAsync(packed, 0, (size_t)600000 * sizeof(float), stream);

        prep_kernel<<<dim3(CS_BLOCKS, 3), 256, 0, stream>>>(x, dst, colsumP,
                                                            (unsigned*)nullptr);
        gru_rows_kernel<<<16, 256, 0, stream>>>(colsumP, iw, Wz, bz, Wr, br, Wh, bh,
                                                Wp, bp, Wo, (unsigned*)nullptr,
                                                (unsigned*)nullptr, (unsigned*)nullptr,
                                                vbuf, out + (size_t)T_STEPS * N_NODES);
        smatvec_kernel<<<dim3(1563, 3), 256, 0, stream>>>(x, vbuf, sbuf);
        edge_kernel<<<dim3(1563, 3), 256, 0, stream>>>(src, dst, sbuf, packed);
        out_kernel<<<1172, 256, 0, stream>>>(packed, bo, out);
    }
}

// Round 16
// 92.432 us; speedup vs baseline: 1.1891x; 1.0877x over previous
//
#include <hip/hip_runtime.h>
#include <math.h>

#define T_STEPS 3
#define N_NODES 100000
#define N_EDGES 1600000
#define N_E4    (N_EDGES / 4)
#define D 64

#define CS_BLOCKS 391       // ceil(100000/256) colsum blocks per t (256 rows each)

// Bucket parameters: 512-node buckets
#define BKT_BITS 9
#define BKT_SIZE 512
#define NBKT 196            // ceil(100000/512)
#define NBKT_PAD 256
#define QSCALE 65536.0f     // 2^16
#define QINV   (1.0f / 65536.0f)

// Chunk parameters: 8192 edges per chunk, chunk == scatter block (1024 thr)
#define SC_EPB 8192
#define SC_I4  2048
#define SC_CHUNKS 196       // ceil(1.6M / 8192)

// smatvec-in-K3: 1024 threads, 4 lanes/row -> 256 rows/block
#define SMV_BLOCKS 391      // ceil(100000/256)

// GRU-rows parameters
#define GR_PAD 68

// Fallback parameters
#define PACK_SCALE 1048576.0f
#define PACK_INV   (1.0f / 1048576.0f)

// ---------------------------------------------------------------------------
// FAST ws layout (float offsets) — atomic-free, no memsets:
//   [0,4800000)        recs[3][E] u32   overlaid (dead before K3):
//        [0,75072)         colsumP[3][391][64]
//        [150144,300672)   histChunk[3][196][256] u32
//   [4800000,4950528)  chunkPref[3][196][256] u32
//   [4950528,4951296)  bstart[3][256] u32
//   [4951296,4951488)  v[3][64]
//   [4951488,5251488)  s[3][N]
// rec format: (dst&511)<<17 | src   (src < 2^17)
// recs layout: bucket-contiguous per t (scatter writes ~336B runs, accum
// reads coalesced — the sort pays on the write side only).
// ---------------------------------------------------------------------------

// K1: fused prep — blocks [0,391): colsum partials of x_t (256 rows/block);
// blocks [391,587): per-chunk dst bucket histograms (8192 edges/chunk).
__global__ __launch_bounds__(256) void prep_kernel(const float* __restrict__ x,
                                                   const int* __restrict__ dst,
                                                   float* __restrict__ colsumP,
                                                   unsigned* __restrict__ histChunk) {
    const int t = blockIdx.y;
    const int tid = threadIdx.x;
    __shared__ float red[16][64];
    __shared__ unsigned h[NBKT_PAD];

    if (blockIdx.x < CS_BLOCKS) {
        const int q = tid & 15;
        const int g = tid >> 4;
        const float4* xt = (const float4*)(x + (size_t)t * N_NODES * D);
        const int base = blockIdx.x * 256;
        float sx = 0.f, sy = 0.f, sz = 0.f, sw = 0.f;
#pragma unroll 4
        for (int it = 0; it < 16; ++it) {
            const int r = base + g + 16 * it;
            if (r < N_NODES) {
                const float4 vv = xt[(size_t)r * 16 + q];
                sx += vv.x; sy += vv.y; sz += vv.z; sw += vv.w;
            }
        }
        red[g][q * 4 + 0] = sx;
        red[g][q * 4 + 1] = sy;
        red[g][q * 4 + 2] = sz;
        red[g][q * 4 + 3] = sw;
        __syncthreads();
        if (tid < 64) {
            float s = 0.f;
#pragma unroll
            for (int gg = 0; gg < 16; ++gg) s += red[gg][tid];
            colsumP[((size_t)t * CS_BLOCKS + blockIdx.x) * 64 + tid] = s;
        }
    } else {
        const int c = blockIdx.x - CS_BLOCKS;
        h[tid] = 0;
        __syncthreads();
        const int4* dp = (const int4*)(dst + (size_t)t * N_EDGES);
#pragma unroll
        for (int it = 0; it < 8; ++it) {
            const int i4 = c * SC_I4 + it * 256 + tid;
            if (i4 < N_E4) {
                const int4 d = dp[i4];
                atomicAdd(&h[d.x >> BKT_BITS], 1u);
                atomicAdd(&h[d.y >> BKT_BITS], 1u);
                atomicAdd(&h[d.z >> BKT_BITS], 1u);
                atomicAdd(&h[d.w >> BKT_BITS], 1u);
            }
        }
        __syncthreads();
        histChunk[((size_t)t * SC_CHUNKS + c) * NBKT_PAD + tid] = h[tid];
    }
}

__device__ __forceinline__ float fast_sigmoid(float v) {
    return 1.f / (1.f + __expf(-v));
}
__device__ __forceinline__ float fast_tanh(float v) {
    return 1.f - 2.f / (__expf(2.f * v) + 1.f);
}

// K2: blocks 0..15 GRU rows; block 16 bucket-total scan -> bstart;
// blocks 17..208 per-(chunk,bucket) exclusive prefixes -> chunkPref.
__global__ __launch_bounds__(256) void gru_rows_kernel(
    const float* __restrict__ colsumP, const float* __restrict__ iw,
    const float* __restrict__ Wz, const float* __restrict__ bz,
    const float* __restrict__ Wr, const float* __restrict__ br,
    const float* __restrict__ Wh, const float* __restrict__ bh,
    const float* __restrict__ Wp, const float* __restrict__ bp,
    const float* __restrict__ Wo, const unsigned* __restrict__ histChunk,
    unsigned* __restrict__ bstart, unsigned* __restrict__ chunkPref,
    float* __restrict__ v_out, float* __restrict__ w_final) {
    const int tid = threadIdx.x;

    if (blockIdx.x == 16) {
        __shared__ unsigned scn[NBKT_PAD];
        for (int t = 0; t < T_STEPS; ++t) {
            unsigned c = 0;
            for (int k = 0; k < SC_CHUNKS; ++k)
                c += histChunk[((size_t)t * SC_CHUNKS + k) * NBKT_PAD + tid];
            unsigned v = c;
            scn[tid] = v;
            __syncthreads();
            for (int off = 1; off < NBKT_PAD; off <<= 1) {
                const unsigned add = (tid >= off) ? scn[tid - off] : 0u;
                __syncthreads();
                v += add;
                scn[tid] = v;
                __syncthreads();
            }
            bstart[t * NBKT_PAD + tid] = (unsigned)(t * N_EDGES) + (v - c);
            __syncthreads();
        }
        return;
    }
    if (blockIdx.x >= 17) {
        const int idx = blockIdx.x - 17;      // 0..191
        const int t = idx >> 6;
        const int wid = tid >> 6, lane = tid & 63;
        const int b = (idx & 63) * 4 + wid;   // 0..255
        unsigned running = 0;
#pragma unroll
        for (int g = 0; g < 4; ++g) {
            const int c = g * 64 + lane;
            const unsigned val = (c < SC_CHUNKS)
                ? histChunk[((size_t)t * SC_CHUNKS + c) * NBKT_PAD + b] : 0u;
            unsigned incl = val;
#pragma unroll
            for (int off = 1; off < 64; off <<= 1) {
                const unsigned n = __shfl_up(incl, off);
                if (lane >= off) incl += n;
            }
            if (c < SC_CHUNKS)
                chunkPref[((size_t)t * SC_CHUNKS + c) * NBKT_PAD + b] = running + (incl - val);
            running += __shfl(incl, 63);
        }
        return;
    }

    // ---- GRU rows block ----
    __shared__ float BzT[64 * GR_PAD];
    __shared__ float BrT[64 * GR_PAD];
    __shared__ float BhT[64 * GR_PAD];
    __shared__ float w_lds[4 * 64];
    __shared__ float mean_s[192];
    __shared__ float ctx_s[192];
    __shared__ float czrh_s[576];

#pragma unroll
    for (int it = 0; it < 16; ++it) {
        const int idx = it * 256 + tid;
        const int k = idx >> 6, j = idx & 63;
        BzT[j * GR_PAD + k] = Wz[(64 + k) * 64 + j];
        BrT[j * GR_PAD + k] = Wr[(64 + k) * 64 + j];
        BhT[j * GR_PAD + k] = Wh[(64 + k) * 64 + j];
    }
    if (tid < 192) {
        const int t = tid >> 6, j = tid & 63;
        float s = 0.f;
        for (int bx = 0; bx < CS_BLOCKS; ++bx)
            s += colsumP[((size_t)t * CS_BLOCKS + bx) * 64 + j];
        mean_s[tid] = s * (1.f / (float)N_NODES);
    }
    __syncthreads();
    if (tid < 192) {
        const int t = tid >> 6, j = tid & 63;
        float c = bp[j];
        for (int k = 0; k < 64; ++k)
            c = fmaf(mean_s[t * 64 + k], Wp[k * 64 + j], c);
        ctx_s[tid] = c;
    }
    __syncthreads();
    for (int co = (tid >> 6); co < 9; co += 4) {
        const int t = co / 3, m = co - 3 * t, j = tid & 63;
        const float* W = (m == 0) ? Wz : (m == 1) ? Wr : Wh;
        const float* bb = (m == 0) ? bz : (m == 1) ? br : bh;
        float c = bb[j];
        for (int k = 0; k < 64; ++k)
            c = fmaf(ctx_s[t * 64 + k], W[k * 64 + j], c);
        czrh_s[co * 64 + j] = c;
    }
    __syncthreads();

    const int wid = tid >> 6, lane = tid & 63;
    const int row = blockIdx.x * 4 + wid;
    float* wrow = &w_lds[wid * 64];
    float w = iw[row * 64 + lane];
    const float wo = Wo[lane];

    for (int t = 0; t < T_STEPS; ++t) {
        wrow[lane] = w;
        __syncthreads();
        float az = 0.f, ar = 0.f;
#pragma unroll
        for (int k0 = 0; k0 < 64; k0 += 4) {
            const float4 wv = *(const float4*)&wrow[k0];
            const float4 z4 = *(const float4*)&BzT[lane * GR_PAD + k0];
            const float4 r4 = *(const float4*)&BrT[lane * GR_PAD + k0];
            az = fmaf(wv.x, z4.x, az); az = fmaf(wv.y, z4.y, az);
            az = fmaf(wv.z, z4.z, az); az = fmaf(wv.w, z4.w, az);
            ar = fmaf(wv.x, r4.x, ar); ar = fmaf(wv.y, r4.y, ar);
            ar = fmaf(wv.z, r4.z, ar); ar = fmaf(wv.w, r4.w, ar);
        }
        const float z = fast_sigmoid(az + czrh_s[(t * 3 + 0) * 64 + lane]);
        const float r = fast_sigmoid(ar + czrh_s[(t * 3 + 1) * 64 + lane]);
        const float rw = r * w;
        __syncthreads();
        wrow[lane] = rw;
        __syncthreads();
        float ah = 0.f;
#pragma unroll
        for (int k0 = 0; k0 < 64; k0 += 4) {
            const float4 wv = *(const float4*)&wrow[k0];
            const float4 h4 = *(const float4*)&BhT[lane * GR_PAD + k0];
            ah = fmaf(wv.x, h4.x, ah); ah = fmaf(wv.y, h4.y, ah);
            ah = fmaf(wv.z, h4.z, ah); ah = fmaf(wv.w, h4.w, ah);
        }
        const float h = fast_tanh(ah + czrh_s[(t * 3 + 2) * 64 + lane]);
        w = z * w + (1.f - z) * h;
        float vp = w * wo;
        vp += __shfl_xor(vp, 1);
        vp += __shfl_xor(vp, 2);
        vp += __shfl_xor(vp, 4);
        vp += __shfl_xor(vp, 8);
        vp += __shfl_xor(vp, 16);
        vp += __shfl_xor(vp, 32);
        if (lane == 0) v_out[t * 64 + row] = vp;
        __syncthreads();
    }
    w_final[row * 64 + lane] = w;
}

// K3: fused scatter (blocks [0,196)) + smatvec (blocks [196,587)), 1024 thr.
// Scatter: hist -> hybrid wave scan -> rank -> ~336B bucket-run writeout.
__global__ __launch_bounds__(1024) void scat_smv_kernel(
    const float* __restrict__ x, const float* __restrict__ v,
    const int* __restrict__ src, const int* __restrict__ dst,
    const unsigned* __restrict__ bstart, const unsigned* __restrict__ chunkPref,
    unsigned* __restrict__ recs, float* __restrict__ s) {
    const int t = blockIdx.y;
    const int tid = threadIdx.x;
    __shared__ __align__(16) unsigned char lds_raw[44096];

    if (blockIdx.x >= SC_CHUNKS) {
        // ---- smatvec: 256 rows per block, 4 lanes per row ----
        float* vs = (float*)lds_raw;
        if (tid < 64) vs[tid] = v[t * 64 + tid];
        __syncthreads();
        const int row = (blockIdx.x - SC_CHUNKS) * 256 + (tid >> 2);
        const int l4 = tid & 3;
        if (row < N_NODES) {
            const float4* xr = (const float4*)(x + ((size_t)t * N_NODES + row) * D);
            float acc = 0.f;
#pragma unroll
            for (int i = 0; i < 4; ++i) {
                const int c = i * 4 + l4;
                const float4 xv = xr[c];
                acc += xv.x * vs[c * 4 + 0] + xv.y * vs[c * 4 + 1] +
                       xv.z * vs[c * 4 + 2] + xv.w * vs[c * 4 + 3];
            }
            acc += __shfl_xor(acc, 1);
            acc += __shfl_xor(acc, 2);
            if (l4 == 0) s[(size_t)t * N_NODES + row] = acc;
        }
        return;
    }

    // ---- scatter chunk c (8192 edges) ----
    const int c = blockIdx.x;
    unsigned* recL = (unsigned*)lds_raw;                       // 8192 u32 = 32KB
    unsigned char* bktL = (unsigned char*)(lds_raw + 32768);   // 8192 u8
    unsigned* bh   = (unsigned*)(lds_raw + 40960);             // 256
    unsigned* lofs = bh + 256;                                 // 256
    unsigned* badj = lofs + 256;                               // 256
    unsigned* wsum = badj + 256;                               // 4

    if (tid < NBKT_PAD) bh[tid] = 0;
    __syncthreads();

    const int4* sp = (const int4*)(src + (size_t)t * N_EDGES);
    const int4* dp = (const int4*)(dst + (size_t)t * N_EDGES);

    unsigned rec[8];
    int bkt[8];
#pragma unroll
    for (int k = 0; k < 8; ++k) bkt[k] = -1;

#pragma unroll
    for (int it = 0; it < 2; ++it) {
        const int i4 = c * SC_I4 + it * 1024 + tid;
        if (i4 < N_E4) {
            const int4 sv = sp[i4];
            const int4 dv = dp[i4];
            const int ss[4] = {sv.x, sv.y, sv.z, sv.w};
            const int dd[4] = {dv.x, dv.y, dv.z, dv.w};
#pragma unroll
            for (int j = 0; j < 4; ++j) {
                const int b = dd[j] >> BKT_BITS;
                rec[it * 4 + j] = ((unsigned)(dd[j] & (BKT_SIZE - 1)) << 17) |
                                  (unsigned)ss[j];
                bkt[it * 4 + j] = b;
                atomicAdd(&bh[b], 1u);
            }
        }
    }
    __syncthreads();
    // hybrid exclusive scan over 256 buckets: 4 waves x 64 + wave-sum combine
    unsigned cnt = 0, incl = 0;
    if (tid < NBKT_PAD) {
        cnt = bh[tid];
        incl = cnt;
#pragma unroll
        for (int off = 1; off < 64; off <<= 1) {
            const unsigned n = __shfl_up(incl, off);
            if ((tid & 63) >= off) incl += n;
        }
        if ((tid & 63) == 63) wsum[tid >> 6] = incl;
    }
    __syncthreads();
    if (tid < NBKT_PAD) {
        const int wv = tid >> 6;
        unsigned offs = 0;
#pragma unroll
        for (int k = 0; k < 3; ++k)
            if (k < wv) offs += wsum[k];
        const unsigned ex = offs + incl - cnt;
        lofs[tid] = ex;
        const unsigned base = bstart[t * NBKT_PAD + tid] +
                              chunkPref[((size_t)t * SC_CHUNKS + c) * NBKT_PAD + tid];
        badj[tid] = base - ex;   // mod 2^32 ok
    }
    __syncthreads();
#pragma unroll
    for (int k = 0; k < 8; ++k) {
        if (bkt[k] >= 0) {
            const unsigned pos = atomicAdd(&lofs[bkt[k]], 1u);
            recL[pos] = rec[k];
            bktL[pos] = (unsigned char)bkt[k];
        }
    }
    __syncthreads();
    const int nrec = min(SC_EPB, N_EDGES - c * SC_EPB);
    for (int i = tid; i < nrec; i += 1024) {
        const unsigned b = bktL[i];
        recs[badj[b] + (unsigned)i] = recL[i];
    }
}

// K4: per-bucket accumulate — coalesced contiguous record reads,
// gather s[src] (L2), integer u64 LDS bins (deterministic), finalize.
__global__ __launch_bounds__(256) void accum_kernel(const unsigned* __restrict__ recs,
                                                    const unsigned* __restrict__ start,
                                                    const float* __restrict__ s,
                                                    const float* __restrict__ bo,
                                                    float* __restrict__ out) {
    const int b = blockIdx.x;
    const int t = blockIdx.y;
    const int tid = threadIdx.x;
    __shared__ unsigned long long bins[BKT_SIZE];
    bins[tid] = 0ULL;
    bins[tid + 256] = 0ULL;
    __syncthreads();
    const float* st = s + (size_t)t * N_NODES;
    const unsigned s0 = start[t * NBKT_PAD + b];
    const unsigned s1 = start[t * NBKT_PAD + b + 1];
    for (unsigned i = s0 + tid; i < s1; i += 256) {
        const unsigned rec = recs[i];
        const unsigned dl = rec >> 17;
        const long long q = llrintf(st[rec & 0x1FFFFu] * QSCALE);
        atomicAdd(&bins[dl],
                  (unsigned long long)((1ULL << 41) + (unsigned long long)q));
    }
    __syncthreads();
    const float bo0 = bo[0];
#pragma unroll
    for (int k = 0; k < 2; ++k) {
        const int i = tid + k * 256;
        const int node = b * BKT_SIZE + i;
        if (node < N_NODES) {
            const unsigned long long tot = bins[i];
            const unsigned long long deg = (tot + (1ULL << 40)) >> 41;
            const long long rem = (long long)(tot - (deg << 41));
            const float acc = (float)rem * QINV;
            out[(size_t)t * N_NODES + node] = bo0 + acc / fmaxf((float)deg, 1.f);
        }
    }
}

// ---------- fallback path: packed global atomics ----------

__global__ __launch_bounds__(256) void smatvec_kernel(const float* __restrict__ x,
                                                      const float* __restrict__ v,
                                                      float* __restrict__ s) {
    const int t = blockIdx.y;
    const int tid = threadIdx.x;
    const int l4 = tid & 3;
    const int rloc = tid >> 2;
    __shared__ float vs[64];
    if (tid < 64) vs[tid] = v[t * 64 + tid];
    __syncthreads();
    const int row = blockIdx.x * 64 + rloc;
    if (row < N_NODES) {
        const float4* xr = (const float4*)(x + ((size_t)t * N_NODES + row) * D);
        float acc = 0.f;
#pragma unroll
        for (int i = 0; i < 4; ++i) {
            const int c = i * 4 + l4;
            const float4 xv = xr[c];
            acc += xv.x * vs[c * 4 + 0] + xv.y * vs[c * 4 + 1] +
                   xv.z * vs[c * 4 + 2] + xv.w * vs[c * 4 + 3];
        }
        acc += __shfl_xor(acc, 1);
        acc += __shfl_xor(acc, 2);
        if (l4 == 0) s[(size_t)t * N_NODES + row] = acc;
    }
}

__global__ __launch_bounds__(256) void edge_kernel(const int* __restrict__ src,
                                                   const int* __restrict__ dst,
                                                   const float* __restrict__ s,
                                                   unsigned long long* __restrict__ packed) {
    const int t = blockIdx.y;
    const int e4 = blockIdx.x * 256 + threadIdx.x;
    if (e4 * 4 >= N_EDGES) return;
    const int4* sp = (const int4*)(src + (size_t)t * N_EDGES);
    const int4* dp = (const int4*)(dst + (size_t)t * N_EDGES);
    const float* st = s + (size_t)t * N_NODES;
    unsigned long long* pk = packed + (size_t)t * N_NODES;
    const int4 s4 = sp[e4];
    const int4 d4 = dp[e4];
    const float v0 = st[s4.x], v1 = st[s4.y], v2 = st[s4.z], v3 = st[s4.w];
    const unsigned long long base = 1ULL << 41;
    atomicAdd(&pk[d4.x], base + (unsigned long long)(long long)llrintf(v0 * PACK_SCALE));
    atomicAdd(&pk[d4.y], base + (unsigned long long)(long long)llrintf(v1 * PACK_SCALE));
    atomicAdd(&pk[d4.z], base + (unsigned long long)(long long)llrintf(v2 * PACK_SCALE));
    atomicAdd(&pk[d4.w], base + (unsigned long long)(long long)llrintf(v3 * PACK_SCALE));
}

__global__ __launch_bounds__(256) void out_kernel(const unsigned long long* __restrict__ packed,
                                                  const float* __restrict__ bo,
                                                  float* __restrict__ out) {
    const int i = blockIdx.x * 256 + threadIdx.x;
    if (i < T_STEPS * N_NODES) {
        const unsigned long long tot = packed[i];
        const unsigned long long deg = (tot + (1ULL << 40)) >> 41;
        const long long rem = (long long)(tot - (deg << 41));
        const float acc = (float)rem * PACK_INV;
        out[i] = bo[0] + acc / fmaxf((float)deg, 1.0f);
    }
}

extern "C" void kernel_launch(void* const* d_in, const int* in_sizes, int n_in,
                              void* d_out, int out_size, void* d_ws, size_t ws_size,
                              hipStream_t stream) {
    const float* x  = (const float*)d_in[0];
    const int* src  = (const int*)d_in[1];
    const int* dst  = (const int*)d_in[2];
    const float* iw = (const float*)d_in[3];
    const float* Wz = (const float*)d_in[4];
    const float* bz = (const float*)d_in[5];
    const float* Wr = (const float*)d_in[6];
    const float* br = (const float*)d_in[7];
    const float* Wh = (const float*)d_in[8];
    const float* bh = (const float*)d_in[9];
    const float* Wp = (const float*)d_in[10];
    const float* bp = (const float*)d_in[11];
    const float* Wo = (const float*)d_in[12];
    const float* bo = (const float*)d_in[13];
    float* out = (float*)d_out;   // [3*N outs][64*64 w_final]
    float* ws  = (float*)d_ws;

    const size_t FAST_NEED = (size_t)5251488 * sizeof(float);
    if (ws_size >= FAST_NEED) {
        unsigned* recs      = (unsigned*)ws;              // [0,4800000)
        float* colsumP      = ws;                         // [0,75072) dead before K3
        unsigned* histChunk = (unsigned*)(ws + 150144);   // [150144,300672) dead before K3
        unsigned* chunkPref = (unsigned*)(ws + 4800000);  // 150528 u32
        unsigned* bstart    = (unsigned*)(ws + 4950528);  // 768 u32
        float* vbuf         = ws + 4951296;               // 192
        float* sbuf         = ws + 4951488;               // 300000

        prep_kernel<<<dim3(CS_BLOCKS + SC_CHUNKS, 3), 256, 0, stream>>>(x, dst,
                                                                        colsumP, histChunk);
        gru_rows_kernel<<<209, 256, 0, stream>>>(colsumP, iw, Wz, bz, Wr, br, Wh, bh,
                                                 Wp, bp, Wo, histChunk, bstart, chunkPref,
                                                 vbuf, out + (size_t)T_STEPS * N_NODES);
        scat_smv_kernel<<<dim3(SC_CHUNKS + SMV_BLOCKS, 3), 1024, 0, stream>>>(
            x, vbuf, src, dst, bstart, chunkPref, recs, sbuf);
        accum_kernel<<<dim3(NBKT, 3), 256, 0, stream>>>(recs, bstart, sbuf, bo, out);
    } else {
        float* colsumP = ws;                                        // 75072
        float* vbuf    = ws + 150144;                               // 192
        float* sbuf    = ws + 150336;                               // 300000
        unsigned long long* packed = (unsigned long long*)(ws + 450336); // 300000 u64

        hipMemsetAsync(packed, 0, (size_t)600000 * sizeof(float), stream);

        prep_kernel<<<dim3(CS_BLOCKS, 3), 256, 0, stream>>>(x, dst, colsumP,
                                                            (unsigned*)nullptr);
        gru_rows_kernel<<<16, 256, 0, stream>>>(colsumP, iw, Wz, bz, Wr, br, Wh, bh,
                                                Wp, bp, Wo, (unsigned*)nullptr,
                                                (unsigned*)nullptr, (unsigned*)nullptr,
                                                vbuf, out + (size_t)T_STEPS * N_NODES);
        smatvec_kernel<<<dim3(1563, 3), 256, 0, stream>>>(x, vbuf, sbuf);
        edge_kernel<<<dim3(1563, 3), 256, 0, stream>>>(src, dst, sbuf, packed);
        out_kernel<<<1172, 256, 0, stream>>>(packed, bo, out);
    }
}

// Round 17
// 89.493 us; speedup vs baseline: 1.2282x; 1.0328x over previous
//
#include <hip/hip_runtime.h>
#include <math.h>

#define T_STEPS 3
#define N_NODES 100000
#define N_EDGES 1600000
#define N_E4    (N_EDGES / 4)
#define D 64

#define CS_BLOCKS 391       // ceil(100000/256) colsum blocks per t (256 rows each)

// Bucket parameters: 512-node buckets
#define BKT_BITS 9
#define BKT_SIZE 512
#define NBKT 196            // ceil(100000/512)
#define NBKT_PAD 256
#define QSCALE 65536.0f     // 2^16
#define QINV   (1.0f / 65536.0f)

// Chunk parameters: 12288 edges per chunk, chunk == scatter block (1024 thr)
#define SC_EPB 12288
#define SC_I4  3072
#define SC_CHUNKS 131       // ceil(400000 i4 / 3072)

// smatvec-in-K3: 1024 threads, 4 lanes/row -> 256 rows/block
#define SMV_BLOCKS 391      // ceil(100000/256)

// GRU-rows parameters
#define GR_PAD 68

// Fallback parameters
#define PACK_SCALE 1048576.0f
#define PACK_INV   (1.0f / 1048576.0f)

// ---------------------------------------------------------------------------
// FAST ws layout (float offsets) — atomic-free, no memsets:
//   [0,4800000)        recs[3][E] u32   overlaid (dead before K3):
//        [0,75072)         colsumP[3][391][64]
//        [150144,250752)   histChunk[3][131][256] u32
//   [4800000,4900608)  chunkPref[3][131][256] u32
//   [4900608,4901376)  bstart[3][256] u32
//   [4901376,4901568)  v[3][64]
//   [4901568,5201568)  s[3][N]
// rec format: (dst&511)<<17 | src   (src < 2^17)
// recs layout: bucket-contiguous per t (scatter writes ~250B runs, accum
// reads coalesced — the sort pays on the write side only).
// ---------------------------------------------------------------------------

// K1: fused prep — blocks [0,391): colsum partials of x_t (256 rows/block);
// blocks [391,522): per-chunk dst bucket histograms (12288 edges/chunk).
__global__ __launch_bounds__(256) void prep_kernel(const float* __restrict__ x,
                                                   const int* __restrict__ dst,
                                                   float* __restrict__ colsumP,
                                                   unsigned* __restrict__ histChunk) {
    const int t = blockIdx.y;
    const int tid = threadIdx.x;
    __shared__ float red[16][64];
    __shared__ unsigned h[NBKT_PAD];

    if (blockIdx.x < CS_BLOCKS) {
        const int q = tid & 15;
        const int g = tid >> 4;
        const float4* xt = (const float4*)(x + (size_t)t * N_NODES * D);
        const int base = blockIdx.x * 256;
        float sx = 0.f, sy = 0.f, sz = 0.f, sw = 0.f;
#pragma unroll 4
        for (int it = 0; it < 16; ++it) {
            const int r = base + g + 16 * it;
            if (r < N_NODES) {
                const float4 vv = xt[(size_t)r * 16 + q];
                sx += vv.x; sy += vv.y; sz += vv.z; sw += vv.w;
            }
        }
        red[g][q * 4 + 0] = sx;
        red[g][q * 4 + 1] = sy;
        red[g][q * 4 + 2] = sz;
        red[g][q * 4 + 3] = sw;
        __syncthreads();
        if (tid < 64) {
            float s = 0.f;
#pragma unroll
            for (int gg = 0; gg < 16; ++gg) s += red[gg][tid];
            colsumP[((size_t)t * CS_BLOCKS + blockIdx.x) * 64 + tid] = s;
        }
    } else {
        const int c = blockIdx.x - CS_BLOCKS;
        h[tid] = 0;
        __syncthreads();
        const int4* dp = (const int4*)(dst + (size_t)t * N_EDGES);
#pragma unroll
        for (int it = 0; it < 12; ++it) {
            const int i4 = c * SC_I4 + it * 256 + tid;
            if (i4 < N_E4) {
                const int4 d = dp[i4];
                atomicAdd(&h[d.x >> BKT_BITS], 1u);
                atomicAdd(&h[d.y >> BKT_BITS], 1u);
                atomicAdd(&h[d.z >> BKT_BITS], 1u);
                atomicAdd(&h[d.w >> BKT_BITS], 1u);
            }
        }
        __syncthreads();
        histChunk[((size_t)t * SC_CHUNKS + c) * NBKT_PAD + tid] = h[tid];
    }
}

__device__ __forceinline__ float fast_sigmoid(float v) {
    return 1.f / (1.f + __expf(-v));
}
__device__ __forceinline__ float fast_tanh(float v) {
    return 1.f - 2.f / (__expf(2.f * v) + 1.f);
}

// K2: blocks 0..15 GRU rows; block 16 bucket-total scan -> bstart;
// blocks 17..208 per-(chunk,bucket) exclusive prefixes -> chunkPref.
__global__ __launch_bounds__(256) void gru_rows_kernel(
    const float* __restrict__ colsumP, const float* __restrict__ iw,
    const float* __restrict__ Wz, const float* __restrict__ bz,
    const float* __restrict__ Wr, const float* __restrict__ br,
    const float* __restrict__ Wh, const float* __restrict__ bh,
    const float* __restrict__ Wp, const float* __restrict__ bp,
    const float* __restrict__ Wo, const unsigned* __restrict__ histChunk,
    unsigned* __restrict__ bstart, unsigned* __restrict__ chunkPref,
    float* __restrict__ v_out, float* __restrict__ w_final) {
    const int tid = threadIdx.x;

    if (blockIdx.x == 16) {
        __shared__ unsigned scn[NBKT_PAD];
        for (int t = 0; t < T_STEPS; ++t) {
            unsigned c = 0;
            for (int k = 0; k < SC_CHUNKS; ++k)
                c += histChunk[((size_t)t * SC_CHUNKS + k) * NBKT_PAD + tid];
            unsigned v = c;
            scn[tid] = v;
            __syncthreads();
            for (int off = 1; off < NBKT_PAD; off <<= 1) {
                const unsigned add = (tid >= off) ? scn[tid - off] : 0u;
                __syncthreads();
                v += add;
                scn[tid] = v;
                __syncthreads();
            }
            bstart[t * NBKT_PAD + tid] = (unsigned)(t * N_EDGES) + (v - c);
            __syncthreads();
        }
        return;
    }
    if (blockIdx.x >= 17) {
        const int idx = blockIdx.x - 17;      // 0..191
        const int t = idx >> 6;
        const int wid = tid >> 6, lane = tid & 63;
        const int b = (idx & 63) * 4 + wid;   // 0..255
        unsigned running = 0;
#pragma unroll
        for (int g = 0; g < 3; ++g) {
            const int c = g * 64 + lane;
            const unsigned val = (c < SC_CHUNKS)
                ? histChunk[((size_t)t * SC_CHUNKS + c) * NBKT_PAD + b] : 0u;
            unsigned incl = val;
#pragma unroll
            for (int off = 1; off < 64; off <<= 1) {
                const unsigned n = __shfl_up(incl, off);
                if (lane >= off) incl += n;
            }
            if (c < SC_CHUNKS)
                chunkPref[((size_t)t * SC_CHUNKS + c) * NBKT_PAD + b] = running + (incl - val);
            running += __shfl(incl, 63);
        }
        return;
    }

    // ---- GRU rows block ----
    __shared__ float BzT[64 * GR_PAD];
    __shared__ float BrT[64 * GR_PAD];
    __shared__ float BhT[64 * GR_PAD];
    __shared__ float w_lds[4 * 64];
    __shared__ float mean_s[192];
    __shared__ float ctx_s[192];
    __shared__ float czrh_s[576];

#pragma unroll
    for (int it = 0; it < 16; ++it) {
        const int idx = it * 256 + tid;
        const int k = idx >> 6, j = idx & 63;
        BzT[j * GR_PAD + k] = Wz[(64 + k) * 64 + j];
        BrT[j * GR_PAD + k] = Wr[(64 + k) * 64 + j];
        BhT[j * GR_PAD + k] = Wh[(64 + k) * 64 + j];
    }
    if (tid < 192) {
        const int t = tid >> 6, j = tid & 63;
        float s = 0.f;
        for (int bx = 0; bx < CS_BLOCKS; ++bx)
            s += colsumP[((size_t)t * CS_BLOCKS + bx) * 64 + j];
        mean_s[tid] = s * (1.f / (float)N_NODES);
    }
    __syncthreads();
    if (tid < 192) {
        const int t = tid >> 6, j = tid & 63;
        float c = bp[j];
        for (int k = 0; k < 64; ++k)
            c = fmaf(mean_s[t * 64 + k], Wp[k * 64 + j], c);
        ctx_s[tid] = c;
    }
    __syncthreads();
    for (int co = (tid >> 6); co < 9; co += 4) {
        const int t = co / 3, m = co - 3 * t, j = tid & 63;
        const float* W = (m == 0) ? Wz : (m == 1) ? Wr : Wh;
        const float* bb = (m == 0) ? bz : (m == 1) ? br : bh;
        float c = bb[j];
        for (int k = 0; k < 64; ++k)
            c = fmaf(ctx_s[t * 64 + k], W[k * 64 + j], c);
        czrh_s[co * 64 + j] = c;
    }
    __syncthreads();

    const int wid = tid >> 6, lane = tid & 63;
    const int row = blockIdx.x * 4 + wid;
    float* wrow = &w_lds[wid * 64];
    float w = iw[row * 64 + lane];
    const float wo = Wo[lane];

    for (int t = 0; t < T_STEPS; ++t) {
        wrow[lane] = w;
        __syncthreads();
        float az = 0.f, ar = 0.f;
#pragma unroll
        for (int k0 = 0; k0 < 64; k0 += 4) {
            const float4 wv = *(const float4*)&wrow[k0];
            const float4 z4 = *(const float4*)&BzT[lane * GR_PAD + k0];
            const float4 r4 = *(const float4*)&BrT[lane * GR_PAD + k0];
            az = fmaf(wv.x, z4.x, az); az = fmaf(wv.y, z4.y, az);
            az = fmaf(wv.z, z4.z, az); az = fmaf(wv.w, z4.w, az);
            ar = fmaf(wv.x, r4.x, ar); ar = fmaf(wv.y, r4.y, ar);
            ar = fmaf(wv.z, r4.z, ar); ar = fmaf(wv.w, r4.w, ar);
        }
        const float z = fast_sigmoid(az + czrh_s[(t * 3 + 0) * 64 + lane]);
        const float r = fast_sigmoid(ar + czrh_s[(t * 3 + 1) * 64 + lane]);
        const float rw = r * w;
        __syncthreads();
        wrow[lane] = rw;
        __syncthreads();
        float ah = 0.f;
#pragma unroll
        for (int k0 = 0; k0 < 64; k0 += 4) {
            const float4 wv = *(const float4*)&wrow[k0];
            const float4 h4 = *(const float4*)&BhT[lane * GR_PAD + k0];
            ah = fmaf(wv.x, h4.x, ah); ah = fmaf(wv.y, h4.y, ah);
            ah = fmaf(wv.z, h4.z, ah); ah = fmaf(wv.w, h4.w, ah);
        }
        const float h = fast_tanh(ah + czrh_s[(t * 3 + 2) * 64 + lane]);
        w = z * w + (1.f - z) * h;
        float vp = w * wo;
        vp += __shfl_xor(vp, 1);
        vp += __shfl_xor(vp, 2);
        vp += __shfl_xor(vp, 4);
        vp += __shfl_xor(vp, 8);
        vp += __shfl_xor(vp, 16);
        vp += __shfl_xor(vp, 32);
        if (lane == 0) v_out[t * 64 + row] = vp;
        __syncthreads();
    }
    w_final[row * 64 + lane] = w;
}

// K3: fused scatter (blocks [0,131)) + smatvec (blocks [131,522)), 1024 thr.
// Scatter: hist -> hybrid wave scan -> rank -> ~250B bucket-run writeout.
__global__ __launch_bounds__(1024) void scat_smv_kernel(
    const float* __restrict__ x, const float* __restrict__ v,
    const int* __restrict__ src, const int* __restrict__ dst,
    const unsigned* __restrict__ bstart, const unsigned* __restrict__ chunkPref,
    unsigned* __restrict__ recs, float* __restrict__ s) {
    const int t = blockIdx.y;
    const int tid = threadIdx.x;
    __shared__ __align__(16) unsigned char lds_raw[64528];

    if (blockIdx.x >= SC_CHUNKS) {
        // ---- smatvec: 256 rows per block, 4 lanes per row ----
        float* vs = (float*)lds_raw;
        if (tid < 64) vs[tid] = v[t * 64 + tid];
        __syncthreads();
        const int row = (blockIdx.x - SC_CHUNKS) * 256 + (tid >> 2);
        const int l4 = tid & 3;
        if (row < N_NODES) {
            const float4* xr = (const float4*)(x + ((size_t)t * N_NODES + row) * D);
            float acc = 0.f;
#pragma unroll
            for (int i = 0; i < 4; ++i) {
                const int c = i * 4 + l4;
                const float4 xv = xr[c];
                acc += xv.x * vs[c * 4 + 0] + xv.y * vs[c * 4 + 1] +
                       xv.z * vs[c * 4 + 2] + xv.w * vs[c * 4 + 3];
            }
            acc += __shfl_xor(acc, 1);
            acc += __shfl_xor(acc, 2);
            if (l4 == 0) s[(size_t)t * N_NODES + row] = acc;
        }
        return;
    }

    // ---- scatter chunk c (12288 edges) ----
    const int c = blockIdx.x;
    unsigned* recL = (unsigned*)lds_raw;                       // 12288 u32 = 48KB
    unsigned char* bktL = (unsigned char*)(lds_raw + 49152);   // 12288 u8
    unsigned* bh   = (unsigned*)(lds_raw + 61440);             // 256
    unsigned* lofs = bh + 256;                                 // 256
    unsigned* badj = lofs + 256;                               // 256
    unsigned* wsum = badj + 256;                               // 4

    if (tid < NBKT_PAD) bh[tid] = 0;
    __syncthreads();

    const int4* sp = (const int4*)(src + (size_t)t * N_EDGES);
    const int4* dp = (const int4*)(dst + (size_t)t * N_EDGES);

    unsigned rec[12];
    int bkt[12];
#pragma unroll
    for (int k = 0; k < 12; ++k) bkt[k] = -1;

#pragma unroll
    for (int it = 0; it < 3; ++it) {
        const int i4 = c * SC_I4 + it * 1024 + tid;
        if (i4 < N_E4) {
            const int4 sv = sp[i4];
            const int4 dv = dp[i4];
            const int ss[4] = {sv.x, sv.y, sv.z, sv.w};
            const int dd[4] = {dv.x, dv.y, dv.z, dv.w};
#pragma unroll
            for (int j = 0; j < 4; ++j) {
                const int b = dd[j] >> BKT_BITS;
                rec[it * 4 + j] = ((unsigned)(dd[j] & (BKT_SIZE - 1)) << 17) |
                                  (unsigned)ss[j];
                bkt[it * 4 + j] = b;
                atomicAdd(&bh[b], 1u);
            }
        }
    }
    __syncthreads();
    // hybrid exclusive scan over 256 buckets: 4 waves x 64 + wave-sum combine
    unsigned cnt = 0, incl = 0;
    if (tid < NBKT_PAD) {
        cnt = bh[tid];
        incl = cnt;
#pragma unroll
        for (int off = 1; off < 64; off <<= 1) {
            const unsigned n = __shfl_up(incl, off);
            if ((tid & 63) >= off) incl += n;
        }
        if ((tid & 63) == 63) wsum[tid >> 6] = incl;
    }
    __syncthreads();
    if (tid < NBKT_PAD) {
        const int wv = tid >> 6;
        unsigned offs = 0;
#pragma unroll
        for (int k = 0; k < 3; ++k)
            if (k < wv) offs += wsum[k];
        const unsigned ex = offs + incl - cnt;
        lofs[tid] = ex;
        const unsigned base = bstart[t * NBKT_PAD + tid] +
                              chunkPref[((size_t)t * SC_CHUNKS + c) * NBKT_PAD + tid];
        badj[tid] = base - ex;   // mod 2^32 ok
    }
    __syncthreads();
#pragma unroll
    for (int k = 0; k < 12; ++k) {
        if (bkt[k] >= 0) {
            const unsigned pos = atomicAdd(&lofs[bkt[k]], 1u);
            recL[pos] = rec[k];
            bktL[pos] = (unsigned char)bkt[k];
        }
    }
    __syncthreads();
    const int nrec = min(SC_EPB, N_EDGES - c * SC_EPB);
    for (int i = tid; i < nrec; i += 1024) {
        const unsigned b = bktL[i];
        recs[badj[b] + (unsigned)i] = recL[i];
    }
}

// K4: per-bucket accumulate (512 thr) — coalesced contiguous record reads,
// gather s[src] (L2), integer u64 LDS bins (deterministic), finalize.
__global__ __launch_bounds__(512) void accum_kernel(const unsigned* __restrict__ recs,
                                                    const unsigned* __restrict__ start,
                                                    const float* __restrict__ s,
                                                    const float* __restrict__ bo,
                                                    float* __restrict__ out) {
    const int b = blockIdx.x;
    const int t = blockIdx.y;
    const int tid = threadIdx.x;
    __shared__ unsigned long long bins[BKT_SIZE];
    bins[tid] = 0ULL;
    __syncthreads();
    const float* st = s + (size_t)t * N_NODES;
    const unsigned s0 = start[t * NBKT_PAD + b];
    const unsigned s1 = start[t * NBKT_PAD + b + 1];
    for (unsigned i = s0 + tid; i < s1; i += 512) {
        const unsigned rec = recs[i];
        const unsigned dl = rec >> 17;
        const long long q = llrintf(st[rec & 0x1FFFFu] * QSCALE);
        atomicAdd(&bins[dl],
                  (unsigned long long)((1ULL << 41) + (unsigned long long)q));
    }
    __syncthreads();
    const float bo0 = bo[0];
    const int node = b * BKT_SIZE + tid;
    if (node < N_NODES) {
        const unsigned long long tot = bins[tid];
        const unsigned long long deg = (tot + (1ULL << 40)) >> 41;
        const long long rem = (long long)(tot - (deg << 41));
        const float acc = (float)rem * QINV;
        out[(size_t)t * N_NODES + node] = bo0 + acc / fmaxf((float)deg, 1.f);
    }
}

// ---------- fallback path: packed global atomics ----------

__global__ __launch_bounds__(256) void smatvec_kernel(const float* __restrict__ x,
                                                      const float* __restrict__ v,
                                                      float* __restrict__ s) {
    const int t = blockIdx.y;
    const int tid = threadIdx.x;
    const int l4 = tid & 3;
    const int rloc = tid >> 2;
    __shared__ float vs[64];
    if (tid < 64) vs[tid] = v[t * 64 + tid];
    __syncthreads();
    const int row = blockIdx.x * 64 + rloc;
    if (row < N_NODES) {
        const float4* xr = (const float4*)(x + ((size_t)t * N_NODES + row) * D);
        float acc = 0.f;
#pragma unroll
        for (int i = 0; i < 4; ++i) {
            const int c = i * 4 + l4;
            const float4 xv = xr[c];
            acc += xv.x * vs[c * 4 + 0] + xv.y * vs[c * 4 + 1] +
                   xv.z * vs[c * 4 + 2] + xv.w * vs[c * 4 + 3];
        }
        acc += __shfl_xor(acc, 1);
        acc += __shfl_xor(acc, 2);
        if (l4 == 0) s[(size_t)t * N_NODES + row] = acc;
    }
}

__global__ __launch_bounds__(256) void edge_kernel(const int* __restrict__ src,
                                                   const int* __restrict__ dst,
                                                   const float* __restrict__ s,
                                                   unsigned long long* __restrict__ packed) {
    const int t = blockIdx.y;
    const int e4 = blockIdx.x * 256 + threadIdx.x;
    if (e4 * 4 >= N_EDGES) return;
    const int4* sp = (const int4*)(src + (size_t)t * N_EDGES);
    const int4* dp = (const int4*)(dst + (size_t)t * N_EDGES);
    const float* st = s + (size_t)t * N_NODES;
    unsigned long long* pk = packed + (size_t)t * N_NODES;
    const int4 s4 = sp[e4];
    const int4 d4 = dp[e4];
    const float v0 = st[s4.x], v1 = st[s4.y], v2 = st[s4.z], v3 = st[s4.w];
    const unsigned long long base = 1ULL << 41;
    atomicAdd(&pk[d4.x], base + (unsigned long long)(long long)llrintf(v0 * PACK_SCALE));
    atomicAdd(&pk[d4.y], base + (unsigned long long)(long long)llrintf(v1 * PACK_SCALE));
    atomicAdd(&pk[d4.z], base + (unsigned long long)(long long)llrintf(v2 * PACK_SCALE));
    atomicAdd(&pk[d4.w], base + (unsigned long long)(long long)llrintf(v3 * PACK_SCALE));
}

__global__ __launch_bounds__(256) void out_kernel(const unsigned long long* __restrict__ packed,
                                                  const float* __restrict__ bo,
                                                  float* __restrict__ out) {
    const int i = blockIdx.x * 256 + threadIdx.x;
    if (i < T_STEPS * N_NODES) {
        const unsigned long long tot = packed[i];
        const unsigned long long deg = (tot + (1ULL << 40)) >> 41;
        const long long rem = (long long)(tot - (deg << 41));
        const float acc = (float)rem * PACK_INV;
        out[i] = bo[0] + acc / fmaxf((float)deg, 1.0f);
    }
}

extern "C" void kernel_launch(void* const* d_in, const int* in_sizes, int n_in,
                              void* d_out, int out_size, void* d_ws, size_t ws_size,
                              hipStream_t stream) {
    const float* x  = (const float*)d_in[0];
    const int* src  = (const int*)d_in[1];
    const int* dst  = (const int*)d_in[2];
    const float* iw = (const float*)d_in[3];
    const float* Wz = (const float*)d_in[4];
    const float* bz = (const float*)d_in[5];
    const float* Wr = (const float*)d_in[6];
    const float* br = (const float*)d_in[7];
    const float* Wh = (const float*)d_in[8];
    const float* bh = (const float*)d_in[9];
    const float* Wp = (const float*)d_in[10];
    const float* bp = (const float*)d_in[11];
    const float* Wo = (const float*)d_in[12];
    const float* bo = (const float*)d_in[13];
    float* out = (float*)d_out;   // [3*N outs][64*64 w_final]
    float* ws  = (float*)d_ws;

    const size_t FAST_NEED = (size_t)5201568 * sizeof(float);
    if (ws_size >= FAST_NEED) {
        unsigned* recs      = (unsigned*)ws;              // [0,4800000)
        float* colsumP      = ws;                         // [0,75072) dead before K3
        unsigned* histChunk = (unsigned*)(ws + 150144);   // [150144,250752) dead before K3
        unsigned* chunkPref = (unsigned*)(ws + 4800000);  // 100608 u32
        unsigned* bstart    = (unsigned*)(ws + 4900608);  // 768 u32
        float* vbuf         = ws + 4901376;               // 192
        float* sbuf         = ws + 4901568;               // 300000

        prep_kernel<<<dim3(CS_BLOCKS + SC_CHUNKS, 3), 256, 0, stream>>>(x, dst,
                                                                        colsumP, histChunk);
        gru_rows_kernel<<<209, 256, 0, stream>>>(colsumP, iw, Wz, bz, Wr, br, Wh, bh,
                                                 Wp, bp, Wo, histChunk, bstart, chunkPref,
                                                 vbuf, out + (size_t)T_STEPS * N_NODES);
        scat_smv_kernel<<<dim3(SC_CHUNKS + SMV_BLOCKS, 3), 1024, 0, stream>>>(
            x, vbuf, src, dst, bstart, chunkPref, recs, sbuf);
        accum_kernel<<<dim3(NBKT, 3), 512, 0, stream>>>(recs, bstart, sbuf, bo, out);
    } else {
        float* colsumP = ws;                                        // 75072
        float* vbuf    = ws + 150144;                               // 192
        float* sbuf    = ws + 150336;                               // 300000
        unsigned long long* packed = (unsigned long long*)(ws + 450336); // 300000 u64

        hipMemsetAsync(packed, 0, (size_t)600000 * sizeof(float), stream);

        prep_kernel<<<dim3(CS_BLOCKS, 3), 256, 0, stream>>>(x, dst, colsumP,
                                                            (unsigned*)nullptr);
        gru_rows_kernel<<<16, 256, 0, stream>>>(colsumP, iw, Wz, bz, Wr, br, Wh, bh,
                                                Wp, bp, Wo, (unsigned*)nullptr,
                                                (unsigned*)nullptr, (unsigned*)nullptr,
                                                vbuf, out + (size_t)T_STEPS * N_NODES);
        smatvec_kernel<<<dim3(1563, 3), 256, 0, stream>>>(x, vbuf, sbuf);
        edge_kernel<<<dim3(1563, 3), 256, 0, stream>>>(src, dst, sbuf, packed);
        out_kernel<<<1172, 256, 0, stream>>>(packed, bo, out);
    }
}

// Round 18
// 87.687 us; speedup vs baseline: 1.2535x; 1.0206x over previous
//
#include <hip/hip_runtime.h>
#include <math.h>

#define T_STEPS 3
#define N_NODES 100000
#define N_EDGES 1600000
#define N_E4    (N_EDGES / 4)
#define D 64

#define CS_BLOCKS 391       // ceil(100000/256) colsum blocks per t (256 rows each)

// Bucket parameters: 512-node buckets
#define BKT_BITS 9
#define BKT_SIZE 512
#define NBKT 196            // ceil(100000/512)
#define NBKT_PAD 256
#define QSCALE 65536.0f     // 2^16
#define QINV   (1.0f / 65536.0f)

// Chunk parameters: 12288 edges per chunk, chunk == scatter block (1024 thr)
#define SC_EPB 12288
#define SC_I4  3072
#define SC_CHUNKS 131       // ceil(400000 i4 / 3072)

// smatvec-in-K3: 1024 threads, 4 lanes/row -> 256 rows/block
#define SMV_BLOCKS 391      // ceil(100000/256)

// GRU-rows parameters
#define GR_PAD 68

// Fallback parameters
#define PACK_SCALE 1048576.0f
#define PACK_INV   (1.0f / 1048576.0f)

// ---------------------------------------------------------------------------
// FAST ws layout (float offsets) — atomic-free, no memsets:
//   [0,4800000)        recs[3][E] u32   overlaid (dead before K3):
//        [0,75072)         colsumP[3][391][64]
//   [4800000,4900608)  chunkPref[3][131][256] u32
//   [4900608,4901376)  bstart[3][256] u32
//   [4901376,4901568)  v[3][64]
//   [4901568,5201568)  s[3][N]
//   [5201568,5302176)  histChunk[3][131][256] u32  (NOT overlaid — scatter
//                      reads it while writing recs)
// rec format: (dst&511)<<17 | src   (src < 2^17)
// recs layout: bucket-contiguous per t (scatter writes ~250B runs, accum
// reads coalesced — the sort pays on the write side only).
// ---------------------------------------------------------------------------

// K1: fused prep — blocks [0,391): colsum partials of x_t (256 rows/block);
// blocks [391,522): per-chunk dst bucket histograms (12288 edges/chunk).
__global__ __launch_bounds__(256) void prep_kernel(const float* __restrict__ x,
                                                   const int* __restrict__ dst,
                                                   float* __restrict__ colsumP,
                                                   unsigned* __restrict__ histChunk) {
    const int t = blockIdx.y;
    const int tid = threadIdx.x;
    __shared__ float red[16][64];
    __shared__ unsigned h[NBKT_PAD];

    if (blockIdx.x < CS_BLOCKS) {
        const int q = tid & 15;
        const int g = tid >> 4;
        const float4* xt = (const float4*)(x + (size_t)t * N_NODES * D);
        const int base = blockIdx.x * 256;
        float sx = 0.f, sy = 0.f, sz = 0.f, sw = 0.f;
#pragma unroll 4
        for (int it = 0; it < 16; ++it) {
            const int r = base + g + 16 * it;
            if (r < N_NODES) {
                const float4 vv = xt[(size_t)r * 16 + q];
                sx += vv.x; sy += vv.y; sz += vv.z; sw += vv.w;
            }
        }
        red[g][q * 4 + 0] = sx;
        red[g][q * 4 + 1] = sy;
        red[g][q * 4 + 2] = sz;
        red[g][q * 4 + 3] = sw;
        __syncthreads();
        if (tid < 64) {
            float s = 0.f;
#pragma unroll
            for (int gg = 0; gg < 16; ++gg) s += red[gg][tid];
            colsumP[((size_t)t * CS_BLOCKS + blockIdx.x) * 64 + tid] = s;
        }
    } else {
        const int c = blockIdx.x - CS_BLOCKS;
        h[tid] = 0;
        __syncthreads();
        const int4* dp = (const int4*)(dst + (size_t)t * N_EDGES);
#pragma unroll
        for (int it = 0; it < 12; ++it) {
            const int i4 = c * SC_I4 + it * 256 + tid;
            if (i4 < N_E4) {
                const int4 d = dp[i4];
                atomicAdd(&h[d.x >> BKT_BITS], 1u);
                atomicAdd(&h[d.y >> BKT_BITS], 1u);
                atomicAdd(&h[d.z >> BKT_BITS], 1u);
                atomicAdd(&h[d.w >> BKT_BITS], 1u);
            }
        }
        __syncthreads();
        histChunk[((size_t)t * SC_CHUNKS + c) * NBKT_PAD + tid] = h[tid];
    }
}

__device__ __forceinline__ float fast_sigmoid(float v) {
    return 1.f / (1.f + __expf(-v));
}
__device__ __forceinline__ float fast_tanh(float v) {
    return 1.f - 2.f / (__expf(2.f * v) + 1.f);
}

// K2: blocks 0..15 GRU rows; block 16 bucket-total scan -> bstart;
// blocks 17..208 per-(chunk,bucket) exclusive prefixes -> chunkPref.
__global__ __launch_bounds__(256) void gru_rows_kernel(
    const float* __restrict__ colsumP, const float* __restrict__ iw,
    const float* __restrict__ Wz, const float* __restrict__ bz,
    const float* __restrict__ Wr, const float* __restrict__ br,
    const float* __restrict__ Wh, const float* __restrict__ bh,
    const float* __restrict__ Wp, const float* __restrict__ bp,
    const float* __restrict__ Wo, const unsigned* __restrict__ histChunk,
    unsigned* __restrict__ bstart, unsigned* __restrict__ chunkPref,
    float* __restrict__ v_out, float* __restrict__ w_final) {
    const int tid = threadIdx.x;

    if (blockIdx.x == 16) {
        __shared__ unsigned scn[NBKT_PAD];
        for (int t = 0; t < T_STEPS; ++t) {
            unsigned c = 0;
            for (int k = 0; k < SC_CHUNKS; ++k)
                c += histChunk[((size_t)t * SC_CHUNKS + k) * NBKT_PAD + tid];
            unsigned v = c;
            scn[tid] = v;
            __syncthreads();
            for (int off = 1; off < NBKT_PAD; off <<= 1) {
                const unsigned add = (tid >= off) ? scn[tid - off] : 0u;
                __syncthreads();
                v += add;
                scn[tid] = v;
                __syncthreads();
            }
            bstart[t * NBKT_PAD + tid] = (unsigned)(t * N_EDGES) + (v - c);
            __syncthreads();
        }
        return;
    }
    if (blockIdx.x >= 17) {
        const int idx = blockIdx.x - 17;      // 0..191
        const int t = idx >> 6;
        const int wid = tid >> 6, lane = tid & 63;
        const int b = (idx & 63) * 4 + wid;   // 0..255
        unsigned running = 0;
#pragma unroll
        for (int g = 0; g < 3; ++g) {
            const int c = g * 64 + lane;
            const unsigned val = (c < SC_CHUNKS)
                ? histChunk[((size_t)t * SC_CHUNKS + c) * NBKT_PAD + b] : 0u;
            unsigned incl = val;
#pragma unroll
            for (int off = 1; off < 64; off <<= 1) {
                const unsigned n = __shfl_up(incl, off);
                if (lane >= off) incl += n;
            }
            if (c < SC_CHUNKS)
                chunkPref[((size_t)t * SC_CHUNKS + c) * NBKT_PAD + b] = running + (incl - val);
            running += __shfl(incl, 63);
        }
        return;
    }

    // ---- GRU rows block ----
    __shared__ float BzT[64 * GR_PAD];
    __shared__ float BrT[64 * GR_PAD];
    __shared__ float BhT[64 * GR_PAD];
    __shared__ float w_lds[4 * 64];
    __shared__ float mean_s[192];
    __shared__ float ctx_s[192];
    __shared__ float czrh_s[576];

#pragma unroll
    for (int it = 0; it < 16; ++it) {
        const int idx = it * 256 + tid;
        const int k = idx >> 6, j = idx & 63;
        BzT[j * GR_PAD + k] = Wz[(64 + k) * 64 + j];
        BrT[j * GR_PAD + k] = Wr[(64 + k) * 64 + j];
        BhT[j * GR_PAD + k] = Wh[(64 + k) * 64 + j];
    }
    if (tid < 192) {
        const int t = tid >> 6, j = tid & 63;
        float s = 0.f;
        for (int bx = 0; bx < CS_BLOCKS; ++bx)
            s += colsumP[((size_t)t * CS_BLOCKS + bx) * 64 + j];
        mean_s[tid] = s * (1.f / (float)N_NODES);
    }
    __syncthreads();
    if (tid < 192) {
        const int t = tid >> 6, j = tid & 63;
        float c = bp[j];
        for (int k = 0; k < 64; ++k)
            c = fmaf(mean_s[t * 64 + k], Wp[k * 64 + j], c);
        ctx_s[tid] = c;
    }
    __syncthreads();
    for (int co = (tid >> 6); co < 9; co += 4) {
        const int t = co / 3, m = co - 3 * t, j = tid & 63;
        const float* W = (m == 0) ? Wz : (m == 1) ? Wr : Wh;
        const float* bb = (m == 0) ? bz : (m == 1) ? br : bh;
        float c = bb[j];
        for (int k = 0; k < 64; ++k)
            c = fmaf(ctx_s[t * 64 + k], W[k * 64 + j], c);
        czrh_s[co * 64 + j] = c;
    }
    __syncthreads();

    const int wid = tid >> 6, lane = tid & 63;
    const int row = blockIdx.x * 4 + wid;
    float* wrow = &w_lds[wid * 64];
    float w = iw[row * 64 + lane];
    const float wo = Wo[lane];

    for (int t = 0; t < T_STEPS; ++t) {
        wrow[lane] = w;
        __syncthreads();
        float az = 0.f, ar = 0.f;
#pragma unroll
        for (int k0 = 0; k0 < 64; k0 += 4) {
            const float4 wv = *(const float4*)&wrow[k0];
            const float4 z4 = *(const float4*)&BzT[lane * GR_PAD + k0];
            const float4 r4 = *(const float4*)&BrT[lane * GR_PAD + k0];
            az = fmaf(wv.x, z4.x, az); az = fmaf(wv.y, z4.y, az);
            az = fmaf(wv.z, z4.z, az); az = fmaf(wv.w, z4.w, az);
            ar = fmaf(wv.x, r4.x, ar); ar = fmaf(wv.y, r4.y, ar);
            ar = fmaf(wv.z, r4.z, ar); ar = fmaf(wv.w, r4.w, ar);
        }
        const float z = fast_sigmoid(az + czrh_s[(t * 3 + 0) * 64 + lane]);
        const float r = fast_sigmoid(ar + czrh_s[(t * 3 + 1) * 64 + lane]);
        const float rw = r * w;
        __syncthreads();
        wrow[lane] = rw;
        __syncthreads();
        float ah = 0.f;
#pragma unroll
        for (int k0 = 0; k0 < 64; k0 += 4) {
            const float4 wv = *(const float4*)&wrow[k0];
            const float4 h4 = *(const float4*)&BhT[lane * GR_PAD + k0];
            ah = fmaf(wv.x, h4.x, ah); ah = fmaf(wv.y, h4.y, ah);
            ah = fmaf(wv.z, h4.z, ah); ah = fmaf(wv.w, h4.w, ah);
        }
        const float h = fast_tanh(ah + czrh_s[(t * 3 + 2) * 64 + lane]);
        w = z * w + (1.f - z) * h;
        float vp = w * wo;
        vp += __shfl_xor(vp, 1);
        vp += __shfl_xor(vp, 2);
        vp += __shfl_xor(vp, 4);
        vp += __shfl_xor(vp, 8);
        vp += __shfl_xor(vp, 16);
        vp += __shfl_xor(vp, 32);
        if (lane == 0) v_out[t * 64 + row] = vp;
        __syncthreads();
    }
    w_final[row * 64 + lane] = w;
}

// K3: fused scatter (blocks [0,131)) + smatvec (blocks [131,522)), 1024 thr.
// Scatter: load per-chunk hist (precomputed by prep) -> hybrid wave scan ->
// single fused load+rank+stage pass -> ~250B bucket-run writeout.
__global__ __launch_bounds__(1024) void scat_smv_kernel(
    const float* __restrict__ x, const float* __restrict__ v,
    const int* __restrict__ src, const int* __restrict__ dst,
    const unsigned* __restrict__ bstart, const unsigned* __restrict__ chunkPref,
    const unsigned* __restrict__ histChunk,
    unsigned* __restrict__ recs, float* __restrict__ s) {
    const int t = blockIdx.y;
    const int tid = threadIdx.x;
    __shared__ __align__(16) unsigned char lds_raw[64528];

    if (blockIdx.x >= SC_CHUNKS) {
        // ---- smatvec: 256 rows per block, 4 lanes per row ----
        float* vs = (float*)lds_raw;
        if (tid < 64) vs[tid] = v[t * 64 + tid];
        __syncthreads();
        const int row = (blockIdx.x - SC_CHUNKS) * 256 + (tid >> 2);
        const int l4 = tid & 3;
        if (row < N_NODES) {
            const float4* xr = (const float4*)(x + ((size_t)t * N_NODES + row) * D);
            float acc = 0.f;
#pragma unroll
            for (int i = 0; i < 4; ++i) {
                const int c = i * 4 + l4;
                const float4 xv = xr[c];
                acc += xv.x * vs[c * 4 + 0] + xv.y * vs[c * 4 + 1] +
                       xv.z * vs[c * 4 + 2] + xv.w * vs[c * 4 + 3];
            }
            acc += __shfl_xor(acc, 1);
            acc += __shfl_xor(acc, 2);
            if (l4 == 0) s[(size_t)t * N_NODES + row] = acc;
        }
        return;
    }

    // ---- scatter chunk c (12288 edges) ----
    const int c = blockIdx.x;
    unsigned* recL = (unsigned*)lds_raw;                       // 12288 u32 = 48KB
    unsigned char* bktL = (unsigned char*)(lds_raw + 49152);   // 12288 u8
    unsigned* lofs = (unsigned*)(lds_raw + 61440);             // 256
    unsigned* badj = lofs + 256;                               // 256
    unsigned* wsum = badj + 256;                               // 4

    // local exclusive scan of the PRECOMPUTED chunk histogram (no private hist)
    unsigned cnt = 0, incl = 0;
    if (tid < NBKT_PAD) {
        cnt = histChunk[((size_t)t * SC_CHUNKS + c) * NBKT_PAD + tid];
        incl = cnt;
#pragma unroll
        for (int off = 1; off < 64; off <<= 1) {
            const unsigned n = __shfl_up(incl, off);
            if ((tid & 63) >= off) incl += n;
        }
        if ((tid & 63) == 63) wsum[tid >> 6] = incl;
    }
    __syncthreads();
    if (tid < NBKT_PAD) {
        const int wv = tid >> 6;
        unsigned offs = 0;
#pragma unroll
        for (int k = 0; k < 3; ++k)
            if (k < wv) offs += wsum[k];
        const unsigned ex = offs + incl - cnt;
        lofs[tid] = ex;
        const unsigned base = bstart[t * NBKT_PAD + tid] +
                              chunkPref[((size_t)t * SC_CHUNKS + c) * NBKT_PAD + tid];
        badj[tid] = base - ex;   // mod 2^32 ok
    }
    __syncthreads();
    // fused load + rank + stage (single pass, no per-thread arrays)
    const int4* sp = (const int4*)(src + (size_t)t * N_EDGES);
    const int4* dp = (const int4*)(dst + (size_t)t * N_EDGES);
#pragma unroll
    for (int it = 0; it < 3; ++it) {
        const int i4 = c * SC_I4 + it * 1024 + tid;
        if (i4 < N_E4) {
            const int4 sv = sp[i4];
            const int4 dv = dp[i4];
            const int ss[4] = {sv.x, sv.y, sv.z, sv.w};
            const int dd[4] = {dv.x, dv.y, dv.z, dv.w};
#pragma unroll
            for (int j = 0; j < 4; ++j) {
                const int b = dd[j] >> BKT_BITS;
                const unsigned pos = atomicAdd(&lofs[b], 1u);
                recL[pos] = ((unsigned)(dd[j] & (BKT_SIZE - 1)) << 17) |
                            (unsigned)ss[j];
                bktL[pos] = (unsigned char)b;
            }
        }
    }
    __syncthreads();
    const int nrec = min(SC_EPB, N_EDGES - c * SC_EPB);
    for (int i = tid; i < nrec; i += 1024) {
        const unsigned b = bktL[i];
        recs[badj[b] + (unsigned)i] = recL[i];
    }
}

// K4: per-bucket accumulate (512 thr) — coalesced contiguous record reads,
// gather s[src] (L2), integer u64 LDS bins (deterministic), finalize.
__global__ __launch_bounds__(512) void accum_kernel(const unsigned* __restrict__ recs,
                                                    const unsigned* __restrict__ start,
                                                    const float* __restrict__ s,
                                                    const float* __restrict__ bo,
                                                    float* __restrict__ out) {
    const int b = blockIdx.x;
    const int t = blockIdx.y;
    const int tid = threadIdx.x;
    __shared__ unsigned long long bins[BKT_SIZE];
    bins[tid] = 0ULL;
    __syncthreads();
    const float* st = s + (size_t)t * N_NODES;
    const unsigned s0 = start[t * NBKT_PAD + b];
    const unsigned s1 = start[t * NBKT_PAD + b + 1];
    for (unsigned i = s0 + tid; i < s1; i += 512) {
        const unsigned rec = recs[i];
        const unsigned dl = rec >> 17;
        const long long q = llrintf(st[rec & 0x1FFFFu] * QSCALE);
        atomicAdd(&bins[dl],
                  (unsigned long long)((1ULL << 41) + (unsigned long long)q));
    }
    __syncthreads();
    const float bo0 = bo[0];
    const int node = b * BKT_SIZE + tid;
    if (node < N_NODES) {
        const unsigned long long tot = bins[tid];
        const unsigned long long deg = (tot + (1ULL << 40)) >> 41;
        const long long rem = (long long)(tot - (deg << 41));
        const float acc = (float)rem * QINV;
        out[(size_t)t * N_NODES + node] = bo0 + acc / fmaxf((float)deg, 1.f);
    }
}

// ---------- fallback path: packed global atomics ----------

__global__ __launch_bounds__(256) void smatvec_kernel(const float* __restrict__ x,
                                                      const float* __restrict__ v,
                                                      float* __restrict__ s) {
    const int t = blockIdx.y;
    const int tid = threadIdx.x;
    const int l4 = tid & 3;
    const int rloc = tid >> 2;
    __shared__ float vs[64];
    if (tid < 64) vs[tid] = v[t * 64 + tid];
    __syncthreads();
    const int row = blockIdx.x * 64 + rloc;
    if (row < N_NODES) {
        const float4* xr = (const float4*)(x + ((size_t)t * N_NODES + row) * D);
        float acc = 0.f;
#pragma unroll
        for (int i = 0; i < 4; ++i) {
            const int c = i * 4 + l4;
            const float4 xv = xr[c];
            acc += xv.x * vs[c * 4 + 0] + xv.y * vs[c * 4 + 1] +
                   xv.z * vs[c * 4 + 2] + xv.w * vs[c * 4 + 3];
        }
        acc += __shfl_xor(acc, 1);
        acc += __shfl_xor(acc, 2);
        if (l4 == 0) s[(size_t)t * N_NODES + row] = acc;
    }
}

__global__ __launch_bounds__(256) void edge_kernel(const int* __restrict__ src,
                                                   const int* __restrict__ dst,
                                                   const float* __restrict__ s,
                                                   unsigned long long* __restrict__ packed) {
    const int t = blockIdx.y;
    const int e4 = blockIdx.x * 256 + threadIdx.x;
    if (e4 * 4 >= N_EDGES) return;
    const int4* sp = (const int4*)(src + (size_t)t * N_EDGES);
    const int4* dp = (const int4*)(dst + (size_t)t * N_EDGES);
    const float* st = s + (size_t)t * N_NODES;
    unsigned long long* pk = packed + (size_t)t * N_NODES;
    const int4 s4 = sp[e4];
    const int4 d4 = dp[e4];
    const float v0 = st[s4.x], v1 = st[s4.y], v2 = st[s4.z], v3 = st[s4.w];
    const unsigned long long base = 1ULL << 41;
    atomicAdd(&pk[d4.x], base + (unsigned long long)(long long)llrintf(v0 * PACK_SCALE));
    atomicAdd(&pk[d4.y], base + (unsigned long long)(long long)llrintf(v1 * PACK_SCALE));
    atomicAdd(&pk[d4.z], base + (unsigned long long)(long long)llrintf(v2 * PACK_SCALE));
    atomicAdd(&pk[d4.w], base + (unsigned long long)(long long)llrintf(v3 * PACK_SCALE));
}

__global__ __launch_bounds__(256) void out_kernel(const unsigned long long* __restrict__ packed,
                                                  const float* __restrict__ bo,
                                                  float* __restrict__ out) {
    const int i = blockIdx.x * 256 + threadIdx.x;
    if (i < T_STEPS * N_NODES) {
        const unsigned long long tot = packed[i];
        const unsigned long long deg = (tot + (1ULL << 40)) >> 41;
        const long long rem = (long long)(tot - (deg << 41));
        const float acc = (float)rem * PACK_INV;
        out[i] = bo[0] + acc / fmaxf((float)deg, 1.0f);
    }
}

extern "C" void kernel_launch(void* const* d_in, const int* in_sizes, int n_in,
                              void* d_out, int out_size, void* d_ws, size_t ws_size,
                              hipStream_t stream) {
    const float* x  = (const float*)d_in[0];
    const int* src  = (const int*)d_in[1];
    const int* dst  = (const int*)d_in[2];
    const float* iw = (const float*)d_in[3];
    const float* Wz = (const float*)d_in[4];
    const float* bz = (const float*)d_in[5];
    const float* Wr = (const float*)d_in[6];
    const float* br = (const float*)d_in[7];
    const float* Wh = (const float*)d_in[8];
    const float* bh = (const float*)d_in[9];
    const float* Wp = (const float*)d_in[10];
    const float* bp = (const float*)d_in[11];
    const float* Wo = (const float*)d_in[12];
    const float* bo = (const float*)d_in[13];
    float* out = (float*)d_out;   // [3*N outs][64*64 w_final]
    float* ws  = (float*)d_ws;

    const size_t FAST_NEED = (size_t)5302176 * sizeof(float);
    if (ws_size >= FAST_NEED) {
        unsigned* recs      = (unsigned*)ws;              // [0,4800000)
        float* colsumP      = ws;                         // [0,75072) dead before K3
        unsigned* chunkPref = (unsigned*)(ws + 4800000);  // 100608 u32
        unsigned* bstart    = (unsigned*)(ws + 4900608);  // 768 u32
        float* vbuf         = ws + 4901376;               // 192
        float* sbuf         = ws + 4901568;               // 300000
        unsigned* histChunk = (unsigned*)(ws + 5201568);  // 100608 u32 (not overlaid)

        prep_kernel<<<dim3(CS_BLOCKS + SC_CHUNKS, 3), 256, 0, stream>>>(x, dst,
                                                                        colsumP, histChunk);
        gru_rows_kernel<<<209, 256, 0, stream>>>(colsumP, iw, Wz, bz, Wr, br, Wh, bh,
                                                 Wp, bp, Wo, histChunk, bstart, chunkPref,
                                                 vbuf, out + (size_t)T_STEPS * N_NODES);
        scat_smv_kernel<<<dim3(SC_CHUNKS + SMV_BLOCKS, 3), 1024, 0, stream>>>(
            x, vbuf, src, dst, bstart, chunkPref, histChunk, recs, sbuf);
        accum_kernel<<<dim3(NBKT, 3), 512, 0, stream>>>(recs, bstart, sbuf, bo, out);
    } else {
        float* colsumP = ws;                                        // 75072
        float* vbuf    = ws + 150144;                               // 192
        float* sbuf    = ws + 150336;                               // 300000
        unsigned long long* packed = (unsigned long long*)(ws + 450336); // 300000 u64

        hipMemsetAsync(packed, 0, (size_t)600000 * sizeof(float), stream);

        prep_kernel<<<dim3(CS_BLOCKS, 3), 256, 0, stream>>>(x, dst, colsumP,
                                                            (unsigned*)nullptr);
        gru_rows_kernel<<<16, 256, 0, stream>>>(colsumP, iw, Wz, bz, Wr, br, Wh, bh,
                                                Wp, bp, Wo, (unsigned*)nullptr,
                                                (unsigned*)nullptr, (unsigned*)nullptr,
                                                vbuf, out + (size_t)T_STEPS * N_NODES);
        smatvec_kernel<<<dim3(1563, 3), 256, 0, stream>>>(x, vbuf, sbuf);
        edge_kernel<<<dim3(1563, 3), 256, 0, stream>>>(src, dst, sbuf, packed);
        out_kernel<<<1172, 256, 0, stream>>>(packed, bo, out);
    }
}